// Round 1
// 3802.716 us; speedup vs baseline: 1.0747x; 1.0747x over previous
//
#include <hip/hip_runtime.h>
#include <hip/hip_bf16.h>
#include <stdint.h>
#include <stddef.h>

#define RROWS 55120   // 8*6890 rows
#define DIN   352
#define DP    384     // padded channel dim
#define NBLK  7
#define KD    120     // eigenbasis size
#define KDP   128     // padded
#define BATCH 8
#define NVERT 6890
#define BN_EPS 1e-3f
#define FH_S  16      // split-K chunks for Fh GEMM

typedef __attribute__((ext_vector_type(8))) short short8;
typedef __attribute__((ext_vector_type(4))) float floatx4;

__device__ __forceinline__ short f2bf(float f) {
  union { float f; uint32_t u; } v; v.f = f;
  uint32_t r = (v.u + 0x7fffu + ((v.u >> 16) & 1u)) >> 16;  // RNE
  return (short)r;
}
__device__ __forceinline__ float bf2f(short s) {
  union { uint32_t u; float f; } v; v.u = ((uint32_t)(uint16_t)s) << 16;
  return v.f;
}

// ---------------------------------------------------------------------------
// Weight prep: Wt[blk][n][k] = bf16(W[blk][k][n]), zero-padded 352->384
// ---------------------------------------------------------------------------
__global__ __launch_bounds__(256) void prep_w(const float* __restrict__ W1, const float* __restrict__ W2,
                                              short* __restrict__ W1t, short* __restrict__ W2t) {
  int e = blockIdx.x * 256 + threadIdx.x;
  const float* W = blockIdx.y ? W2 : W1;
  short* Wt = blockIdx.y ? W2t : W1t;
  int blk = e / (DP * DP);
  int rem = e - blk * DP * DP;
  int n = rem / DP;
  int k = rem - n * DP;
  float v = (n < DIN && k < DIN) ? W[(size_t)blk * DIN * DIN + (size_t)k * DIN + n] : 0.f;
  Wt[e] = f2bf(v);
}

// ---------------------------------------------------------------------------
// cast evecs fp32 [b][n][120] -> bf16 [b][n][128] (padded)
// ---------------------------------------------------------------------------
__global__ __launch_bounds__(256) void cast_e(const float* __restrict__ E, short* __restrict__ Eb) {
  int idx = blockIdx.x * 256 + threadIdx.x;
  int u8 = idx & 15;
  int n = idx >> 4;
  if (n >= NVERT) return;
  int b = blockIdx.y;
  short8 o;
  if (u8 < 15) {
    const float* src = E + ((size_t)b * NVERT + n) * KD + u8 * 8;
    #pragma unroll
    for (int j = 0; j < 8; ++j) o[j] = f2bf(src[j]);
  } else {
    #pragma unroll
    for (int j = 0; j < 8; ++j) o[j] = 0;
  }
  *(short8*)(Eb + ((size_t)b * NVERT + n) * KDP + u8 * 8) = o;
}

// ---------------------------------------------------------------------------
// cast input fp32 -> bf16, pad channels to 384; block 0 zeroes statsA
// ---------------------------------------------------------------------------
__global__ __launch_bounds__(192) void cast_in(const float* __restrict__ F, short* __restrict__ X,
                                               float* __restrict__ zbuf) {
  int tid = threadIdx.x;
  if (blockIdx.x == 0)
    for (int z = tid; z < 2 * DP; z += 192) zbuf[z] = 0.f;
  int cg = tid % 48, rl = tid / 48;
  int c0 = cg * 8;
  int row0 = blockIdx.x * 128;
  for (int rr = rl; rr < 128; rr += 4) {
    int row = row0 + rr;
    if (row >= RROWS) break;
    short8 o;
    if (c0 < DIN) {
      const float* src = F + (size_t)row * DIN + c0;
      #pragma unroll
      for (int j = 0; j < 8; ++j) o[j] = f2bf(src[j]);
    } else {
      #pragma unroll
      for (int j = 0; j < 8; ++j) o[j] = 0;
    }
    *(short8*)(X + (size_t)row * DP + c0) = o;
  }
}

// ---------------------------------------------------------------------------
// GEMM: Y[m][n] = A[m][:] @ Wt[n][:] + bias[n]   (bf16 in, bf16 out, fp32 acc)
// fused per-column sum / sumsq atomically into stats
// ---------------------------------------------------------------------------
__global__ __launch_bounds__(256) void gemm_bn(
    const short* __restrict__ A, const short* __restrict__ Bt,
    short* __restrict__ Y, const float* __restrict__ bias,
    float* __restrict__ stats) {
  __shared__ short As[128 * 64];
  __shared__ short Bs[128 * 64];
  const int tid = threadIdx.x;
  const int lane = tid & 63;
  const int w = tid >> 6;
  const int m0 = blockIdx.x * 128;
  const int n0 = blockIdx.y * 128;

  const int rsub = lane >> 3;
  const int gsw = (lane & 7) ^ rsub;

  const short* aSrc[4]; const short* bSrc[4];
  short* aDst[4]; short* bDst[4];
  #pragma unroll
  for (int t = 0; t < 4; ++t) {
    int r = 32 * w + 8 * t + rsub;
    int gm = m0 + r; if (gm >= RROWS) gm = RROWS - 1;
    aSrc[t] = A + (size_t)gm * DP + gsw * 8;
    bSrc[t] = Bt + (size_t)(n0 + r) * DP + gsw * 8;
    aDst[t] = &As[(32 * w + 8 * t) * 64];
    bDst[t] = &Bs[(32 * w + 8 * t) * 64];
  }

  floatx4 acc[4][4];
  #pragma unroll
  for (int i = 0; i < 4; ++i)
    #pragma unroll
    for (int j = 0; j < 4; ++j)
      acc[i][j] = (floatx4){0.f, 0.f, 0.f, 0.f};

  const int l15 = lane & 15;
  const int q = lane >> 4;
  const int wm = 64 * (w >> 1);
  const int wn = 64 * (w & 1);

  for (int kt = 0; kt < DP / 64; ++kt) {
    __syncthreads();
    #pragma unroll
    for (int t = 0; t < 4; ++t) {
      __builtin_amdgcn_global_load_lds((const __attribute__((address_space(1))) void*)(aSrc[t] + kt * 64),
                                       (__attribute__((address_space(3))) void*)aDst[t], 16, 0, 0);
      __builtin_amdgcn_global_load_lds((const __attribute__((address_space(1))) void*)(bSrc[t] + kt * 64),
                                       (__attribute__((address_space(3))) void*)bDst[t], 16, 0, 0);
    }
    __syncthreads();
    #pragma unroll
    for (int ks = 0; ks < 2; ++ks) {
      const int pos8 = ((((ks << 2) | q)) ^ (l15 & 7)) * 8;
      short8 af[4], bfv[4];
      #pragma unroll
      for (int mt = 0; mt < 4; ++mt)
        af[mt] = *(const short8*)&As[(wm + 16 * mt + l15) * 64 + pos8];
      #pragma unroll
      for (int nt = 0; nt < 4; ++nt)
        bfv[nt] = *(const short8*)&Bs[(wn + 16 * nt + l15) * 64 + pos8];
      #pragma unroll
      for (int mt = 0; mt < 4; ++mt)
        #pragma unroll
        for (int nt = 0; nt < 4; ++nt)
          acc[mt][nt] = __builtin_amdgcn_mfma_f32_16x16x32_bf16(af[mt], bfv[nt], acc[mt][nt], 0, 0, 0);
    }
  }

  const int mwb = m0 + wm;
  const int nwb = n0 + wn;
  #pragma unroll
  for (int nt = 0; nt < 4; ++nt) {
    const int n = nwb + 16 * nt + l15;
    const float bv = (n < DIN) ? bias[n] : 0.f;
    float s1 = 0.f, s2 = 0.f;
    #pragma unroll
    for (int mt = 0; mt < 4; ++mt) {
      const int mb = mwb + 16 * mt + 4 * q;
      #pragma unroll
      for (int v = 0; v < 4; ++v) {
        const int m = mb + v;
        if (m < RROWS) {
          float val = acc[mt][nt][v] + bv;
          Y[(size_t)m * DP + n] = f2bf(val);
          s1 += val;
          s2 += val * val;
        }
      }
    }
    s1 += __shfl_xor(s1, 16);
    s2 += __shfl_xor(s2, 16);
    s1 += __shfl_xor(s1, 32);
    s2 += __shfl_xor(s2, 32);
    if (q == 0) {
      atomicAdd(&stats[n], s1);
      atomicAdd(&stats[DP + n], s2);
    }
  }
}

// ---------------------------------------------------------------------------
// ELT1: H = relu(gamma*(Y-mean)*istd + beta); zeroes the other stats buffer
// ---------------------------------------------------------------------------
__global__ __launch_bounds__(192) void elt_bn(
    const short* __restrict__ Yin, short* __restrict__ Hout,
    const float* __restrict__ stats, const float* __restrict__ gamma, const float* __restrict__ beta,
    float* __restrict__ zbuf) {
  int tid = threadIdx.x;
  if (blockIdx.x == 0)
    for (int z = tid; z < 2 * DP; z += 192) zbuf[z] = 0.f;
  int cg = tid % 48, rl = tid / 48;
  int c0 = cg * 8;
  float av[8], bb[8];
  #pragma unroll
  for (int j = 0; j < 8; ++j) {
    int c = c0 + j;
    float mean = stats[c] * (1.f / RROWS);
    float var = stats[DP + c] * (1.f / RROWS) - mean * mean;
    float istd = rsqrtf(var + BN_EPS);
    float g = (c < DIN) ? gamma[c] : 0.f;
    float b = (c < DIN) ? beta[c] : 0.f;
    av[j] = g * istd;
    bb[j] = b - g * istd * mean;
  }
  int row0 = blockIdx.x * 128;
  for (int rr = rl; rr < 128; rr += 4) {
    int row = row0 + rr;
    if (row >= RROWS) break;
    size_t off = (size_t)row * DP + c0;
    short8 y = *(const short8*)(Yin + off);
    short8 h;
    #pragma unroll
    for (int j = 0; j < 8; ++j) {
      float v = av[j] * bf2f(y[j]) + bb[j];
      h[j] = f2bf(fmaxf(v, 0.f));
    }
    *(short8*)(Hout + off) = h;
  }
}

// ---------------------------------------------------------------------------
// ELT2: X = relu(bn(Y) + X); optional fp32 write of result into d_out
// ---------------------------------------------------------------------------
__global__ __launch_bounds__(192) void elt_res(
    const short* __restrict__ Yin, short* __restrict__ X,
    const float* __restrict__ stats, const float* __restrict__ gamma, const float* __restrict__ beta,
    float* __restrict__ zbuf, float* __restrict__ fout) {
  int tid = threadIdx.x;
  if (blockIdx.x == 0)
    for (int z = tid; z < 2 * DP; z += 192) zbuf[z] = 0.f;
  int cg = tid % 48, rl = tid / 48;
  int c0 = cg * 8;
  float av[8], bb[8];
  #pragma unroll
  for (int j = 0; j < 8; ++j) {
    int c = c0 + j;
    float mean = stats[c] * (1.f / RROWS);
    float var = stats[DP + c] * (1.f / RROWS) - mean * mean;
    float istd = rsqrtf(var + BN_EPS);
    float g = (c < DIN) ? gamma[c] : 0.f;
    float b = (c < DIN) ? beta[c] : 0.f;
    av[j] = g * istd;
    bb[j] = b - g * istd * mean;
  }
  int row0 = blockIdx.x * 128;
  for (int rr = rl; rr < 128; rr += 4) {
    int row = row0 + rr;
    if (row >= RROWS) break;
    size_t off = (size_t)row * DP + c0;
    short8 y = *(const short8*)(Yin + off);
    short8 x = *(const short8*)(X + off);
    short8 h;
    float vr[8];
    #pragma unroll
    for (int j = 0; j < 8; ++j) {
      float v = av[j] * bf2f(y[j]) + bb[j] + bf2f(x[j]);
      v = fmaxf(v, 0.f);
      vr[j] = v;
      h[j] = f2bf(v);
    }
    *(short8*)(X + off) = h;
    if (fout != nullptr && c0 < DIN) {
      float4 o0 = make_float4(vr[0], vr[1], vr[2], vr[3]);
      float4 o1 = make_float4(vr[4], vr[5], vr[6], vr[7]);
      *(float4*)(fout + (size_t)row * DIN + c0) = o0;
      *(float4*)(fout + (size_t)row * DIN + c0 + 4) = o1;
    }
  }
}

// ---------------------------------------------------------------------------
// Fh GEMM (bf16 MFMA, split-K, LDS-transpose staging):
//   Fh[u][v] += sum_n E[n][u] * X[n][v]   per batch b
// grid: x = k-chunk (FH_S), y = v-tile (3 of 128), z = batch (8)
// LDS layout [row][72] shorts: 72-pad => ds_read_b128 16B-aligned, <=2-way banks
// ---------------------------------------------------------------------------
__global__ __launch_bounds__(256) void fh_mfma(const short* __restrict__ Eb, const short* __restrict__ X,
                                               float* __restrict__ Fh) {
  __shared__ short Es[128 * 72];
  __shared__ short Xs[128 * 72];
  const int tid = threadIdx.x;
  const int lane = tid & 63;
  const int w = tid >> 6;
  const int b = blockIdx.z;
  const int v0 = blockIdx.y * 128;
  const int chunk = (NVERT + FH_S - 1) / FH_S;  // 431
  const int kbase = blockIdx.x * chunk;
  const int nend = min(kbase + chunk, NVERT);
  const int np = tid & 31;   // n-pair index within 64-tile
  const int ug = tid >> 5;   // 0..7 -> u/v block of 16

  const short* Ebase = Eb + (size_t)b * NVERT * KDP;
  const short* Xbase = X + (size_t)b * NVERT * DP + v0;

  floatx4 acc[4][4];
  #pragma unroll
  for (int i = 0; i < 4; ++i)
    #pragma unroll
    for (int j = 0; j < 4; ++j)
      acc[i][j] = (floatx4){0.f, 0.f, 0.f, 0.f};

  const int l15 = lane & 15;
  const int q = lane >> 4;
  const int wm = 64 * (w >> 1);
  const int wn = 64 * (w & 1);

  const int ntiles = (nend - kbase + 63) >> 6;
  for (int kt = 0; kt < ntiles; ++kt) {
    const int nb = kbase + kt * 64;
    const int n0 = nb + 2 * np;
    const bool ok0 = (n0 < nend);
    const bool ok1 = (n0 + 1 < nend);
    __syncthreads();
    #pragma unroll
    for (int i = 0; i < 2; ++i) {
      const int u0 = ug * 16 + 8 * i;
      short8 z; 
      #pragma unroll
      for (int j = 0; j < 8; ++j) z[j] = 0;
      short8 e0 = z, e1 = z, x0 = z, x1 = z;
      if (ok0) {
        e0 = *(const short8*)(Ebase + (size_t)n0 * KDP + u0);
        x0 = *(const short8*)(Xbase + (size_t)n0 * DP + u0);
      }
      if (ok1) {
        e1 = *(const short8*)(Ebase + (size_t)(n0 + 1) * KDP + u0);
        x1 = *(const short8*)(Xbase + (size_t)(n0 + 1) * DP + u0);
      }
      #pragma unroll
      for (int j = 0; j < 8; ++j) {
        uint32_t ep = (uint32_t)(uint16_t)e0[j] | ((uint32_t)(uint16_t)e1[j] << 16);
        uint32_t xp = (uint32_t)(uint16_t)x0[j] | ((uint32_t)(uint16_t)x1[j] << 16);
        *(uint32_t*)&Es[(u0 + j) * 72 + 2 * np] = ep;
        *(uint32_t*)&Xs[(u0 + j) * 72 + 2 * np] = xp;
      }
    }
    __syncthreads();
    #pragma unroll
    for (int ks = 0; ks < 2; ++ks) {
      const int ko = ks * 32 + q * 8;
      short8 af[4], bfv[4];
      #pragma unroll
      for (int mt = 0; mt < 4; ++mt)
        af[mt] = *(const short8*)&Es[(wm + 16 * mt + l15) * 72 + ko];
      #pragma unroll
      for (int nt = 0; nt < 4; ++nt)
        bfv[nt] = *(const short8*)&Xs[(wn + 16 * nt + l15) * 72 + ko];
      #pragma unroll
      for (int mt = 0; mt < 4; ++mt)
        #pragma unroll
        for (int nt = 0; nt < 4; ++nt)
          acc[mt][nt] = __builtin_amdgcn_mfma_f32_16x16x32_bf16(af[mt], bfv[nt], acc[mt][nt], 0, 0, 0);
    }
  }

  float* Fo = Fh + (size_t)b * (KDP * DP);
  #pragma unroll
  for (int nt = 0; nt < 4; ++nt) {
    const int v = wn + 16 * nt + l15;
    #pragma unroll
    for (int mt = 0; mt < 4; ++mt) {
      const int ub = wm + 16 * mt + 4 * q;
      #pragma unroll
      for (int vi = 0; vi < 4; ++vi) {
        const int u = ub + vi;
        if (u < KD)
          atomicAdd(&Fo[(size_t)u * DP + v0 + v], acc[mt][nt][vi]);
      }
    }
  }
}

// ---------------------------------------------------------------------------
// Gram: mat0=FtF, mat1=FtG, mat2=GtG; Fh rows padded to DP=384 (pad cols are 0)
// ---------------------------------------------------------------------------
__global__ __launch_bounds__(256) void gram_kern(const float* __restrict__ Fh, float* __restrict__ G) {
  __shared__ float As[128 * 33];
  __shared__ float Bs[32 * 132];
  int mat = blockIdx.x, b = blockIdx.y;
  const float* Pa = Fh + (size_t)((mat == 2 ? BATCH : 0) + b) * KDP * DP;
  const float* Pb = Fh + (size_t)((mat == 0 ? 0 : BATCH) + b) * KDP * DP;
  int tid = threadIdx.x;
  int ty = tid >> 4, tx = tid & 15;
  float accv[8][8];
  #pragma unroll
  for (int i = 0; i < 8; ++i)
    #pragma unroll
    for (int j = 0; j < 8; ++j) accv[i][j] = 0.f;
  for (int ch = 0; ch < 12; ++ch) {
    int d0 = ch * 32;
    __syncthreads();
    #pragma unroll
    for (int j = 0; j < 16; ++j) {
      int e = tid + 256 * j;
      int r = e >> 5, c = e & 31;
      float va = (r < KD) ? Pa[(size_t)r * DP + d0 + c] : 0.f;
      float vb = (r < KD) ? Pb[(size_t)r * DP + d0 + c] : 0.f;
      As[r * 33 + c] = va;
      Bs[c * 132 + r] = vb;
    }
    __syncthreads();
    for (int dd = 0; dd < 32; ++dd) {
      float a[8], bv[8];
      #pragma unroll
      for (int i = 0; i < 8; ++i) a[i] = As[(8 * ty + i) * 33 + dd];
      float4 b0 = *(const float4*)&Bs[dd * 132 + 8 * tx];
      float4 b1 = *(const float4*)&Bs[dd * 132 + 8 * tx + 4];
      bv[0] = b0.x; bv[1] = b0.y; bv[2] = b0.z; bv[3] = b0.w;
      bv[4] = b1.x; bv[5] = b1.y; bv[6] = b1.z; bv[7] = b1.w;
      #pragma unroll
      for (int i = 0; i < 8; ++i)
        #pragma unroll
        for (int j = 0; j < 8; ++j)
          accv[i][j] += a[i] * bv[j];
    }
  }
  float* Go = G + (size_t)(b * 3 + mat) * KD * KD;
  #pragma unroll
  for (int i = 0; i < 8; ++i) {
    int k = 8 * ty + i;
    if (k < KD)
      #pragma unroll
      for (int j = 0; j < 8; ++j) {
        int l = 8 * tx + j;
        if (l < KD) Go[k * KD + l] = accv[i][j];
      }
  }
}

// ---------------------------------------------------------------------------
// Cholesky of FtF (sys even) / GtG (sys odd), in-LDS, L + invdiag to global.
// Element-parallel trailing update: the old version had each thread walk a
// serial jj-loop (~60 avg iters x ~135 cyc LDS RMW latency = 8k cyc/pivot ->
// 407 us). Now the (KD-1-p)-triangle is flattened and strided across all 256
// threads (independent iterations -> pipelined LDS ops), diagonal deferred to
// diag[] to avoid a read/write race, pivot column staged in colv[].
// ---------------------------------------------------------------------------
__global__ __launch_bounds__(256) void chol_kern(const float* __restrict__ G, float* __restrict__ Lb,
                                                 float* __restrict__ invd) {
  __shared__ float As[120 * 121];
  __shared__ float diag[KD];
  __shared__ float colv[KD];
  int sys = blockIdx.x;
  int b = sys >> 1;
  int mat = (sys & 1) ? 2 : 0;
  const float* Gm = G + (size_t)(b * 3 + mat) * KD * KD;
  int tid = threadIdx.x;
  for (int e = tid; e < KD * KD; e += 256) {
    int r = e / KD, c = e - r * KD;
    As[r * 121 + c] = Gm[e];
  }
  __syncthreads();
  for (int p = 0; p < KD; ++p) {
    // all threads read the (post-update) diagonal and compute the scale
    float d = As[p * 121 + p];
    float s = sqrtf(d);
    float dinv = 1.f / s;
    if (tid == 0) diag[p] = s;
    // scale pivot column below the diagonal; stage into colv for cheap reads
    for (int i = p + 1 + tid; i < KD; i += 256) {
      float v = As[i * 121 + p] * dinv;
      As[i * 121 + p] = v;
      colv[i] = v;
    }
    __syncthreads();
    // element-parallel rank-1 trailing update over the lower triangle
    int m = KD - 1 - p;                 // rows p+1 .. KD-1
    int tot = (m * (m + 1)) >> 1;
    for (int e = tid; e < tot; e += 256) {
      int r = (int)((sqrtf(8.f * (float)e + 1.f) - 1.f) * 0.5f);
      int base = (r * (r + 1)) >> 1;
      if (base > e) { base -= r; --r; }
      else if (e - base > r) { ++r; base += r; }
      int i = p + 1 + r;
      int j = p + 1 + (e - base);       // j <= i guaranteed
      As[i * 121 + j] -= colv[i] * colv[j];
    }
    __syncthreads();
  }
  // patch deferred diagonal back in, then dump L and inverse diagonal
  if (tid < KD) As[tid * 121 + tid] = diag[tid];
  __syncthreads();
  float* Lo = Lb + (size_t)sys * (KD * 121);
  for (int e = tid; e < KD * 121; e += 256) Lo[e] = As[e];
  if (tid < KD) invd[sys * KD + tid] = 1.f / diag[tid];
}

// ---------------------------------------------------------------------------
// Triangular solves: columns thread-private in LDS -> no barriers.
// ---------------------------------------------------------------------------
__global__ __launch_bounds__(128) void solve_kern(const float* __restrict__ Lb, const float* __restrict__ invd,
                                                  const float* __restrict__ G, float* __restrict__ out) {
  __shared__ float xs[120 * 128];
  int sys = blockIdx.x;
  int b = sys >> 1;
  int which = sys & 1;
  const float* L = Lb + (size_t)sys * (KD * 121);
  const float* iv = invd + sys * KD;
  const float* Bm = G + (size_t)(b * 3 + 1) * KD * KD;  // FtG
  int t = threadIdx.x;
  for (int k = 0; k < KD; ++k)
    xs[k * 128 + t] = (t < KD) ? (which == 0 ? Bm[k * KD + t] : Bm[t * KD + k]) : 0.f;
  for (int k = 0; k < KD; ++k) {
    float s0 = 0.f, s1 = 0.f, s2 = 0.f, s3 = 0.f;
    int j = 0;
    for (; j + 4 <= k; j += 4) {
      s0 += L[k * 121 + j + 0] * xs[(j + 0) * 128 + t];
      s1 += L[k * 121 + j + 1] * xs[(j + 1) * 128 + t];
      s2 += L[k * 121 + j + 2] * xs[(j + 2) * 128 + t];
      s3 += L[k * 121 + j + 3] * xs[(j + 3) * 128 + t];
    }
    for (; j < k; ++j) s0 += L[k * 121 + j] * xs[j * 128 + t];
    xs[k * 128 + t] = (xs[k * 128 + t] - ((s0 + s1) + (s2 + s3))) * iv[k];
  }
  for (int k = KD - 1; k >= 0; --k) {
    float s0 = 0.f, s1 = 0.f, s2 = 0.f, s3 = 0.f;
    int j = k + 1;
    for (; j + 4 <= KD; j += 4) {
      s0 += L[(j + 0) * 121 + k] * xs[(j + 0) * 128 + t];
      s1 += L[(j + 1) * 121 + k] * xs[(j + 1) * 128 + t];
      s2 += L[(j + 2) * 121 + k] * xs[(j + 2) * 128 + t];
      s3 += L[(j + 3) * 121 + k] * xs[(j + 3) * 128 + t];
    }
    for (; j < KD; ++j) s0 += L[j * 121 + k] * xs[j * 128 + t];
    xs[k * 128 + t] = (xs[k * 128 + t] - ((s0 + s1) + (s2 + s3))) * iv[k];
  }
  if (t < KD) {
    float* Co = out + (size_t)which * BATCH * KD * KD + (size_t)b * KD * KD;
    for (int k = 0; k < KD; ++k) Co[t * KD + k] = xs[k * 128 + t];
  }
}

// ---------------------------------------------------------------------------
extern "C" void kernel_launch(void* const* d_in, const int* in_sizes, int n_in,
                              void* d_out, int out_size, void* d_ws, size_t ws_size,
                              hipStream_t stream) {
  (void)in_sizes; (void)n_in; (void)out_size; (void)ws_size;
  const float* feat_x = (const float*)d_in[0];
  const float* feat_y = (const float*)d_in[1];
  const float* evecs_x = (const float*)d_in[2];
  const float* evecs_y = (const float*)d_in[3];
  const float* W1 = (const float*)d_in[4];
  const float* b1 = (const float*)d_in[5];
  const float* W2 = (const float*)d_in[6];
  const float* b2 = (const float*)d_in[7];
  const float* gamma = (const float*)d_in[8];
  const float* beta = (const float*)d_in[9];
  float* out = (float*)d_out;

  char* p = (char*)d_ws;
  auto carve = [&](size_t bytes) { char* r = p; p += (bytes + 255) & ~(size_t)255; return r; };
  short* W1t = (short*)carve(7ull * DP * DP * 2);
  short* W2t = (short*)carve(7ull * DP * DP * 2);
  short* X  = (short*)carve((size_t)RROWS * DP * 2);
  short* T1 = (short*)carve((size_t)RROWS * DP * 2);
  short* T2 = (short*)carve((size_t)RROWS * DP * 2);
  short* Eb = (short*)carve((size_t)BATCH * NVERT * KDP * 2);
  float* stats = (float*)carve(4ull * DP * 4);
  float* Fh = (float*)carve(2ull * BATCH * KDP * DP * 4);
  float* gram = (float*)carve((size_t)BATCH * 3 * KD * KD * 4);
  float* Lb = (float*)carve(16ull * KD * 121 * 4);
  float* invd = (float*)carve(16ull * KD * 4);
  float* statsA = stats;
  float* statsB = stats + 2 * DP;

  hipMemsetAsync(Fh, 0, 2ull * BATCH * KDP * DP * 4, stream);
  prep_w<<<dim3((7 * DP * DP) / 256, 2), 256, 0, stream>>>(W1, W2, W1t, W2t);

  const int MT = (RROWS + 127) / 128;  // 431
  const int ET = (NVERT * 16 + 255) / 256;  // 431
  for (int f = 0; f < 2; ++f) {
    const float* feat = f ? feat_y : feat_x;
    const float* ev = f ? evecs_y : evecs_x;
    float* fxo = out + 2 * BATCH * KD * KD + (size_t)f * RROWS * DIN;
    cast_in<<<MT, 192, 0, stream>>>(feat, X, statsA);
    cast_e<<<dim3(ET, BATCH), 256, 0, stream>>>(ev, Eb);
    for (int blk = 0; blk < NBLK; ++blk) {
      gemm_bn<<<dim3(MT, 3), 256, 0, stream>>>(X, W1t + (size_t)blk * DP * DP, T1, b1 + blk * DIN, statsA);
      elt_bn<<<MT, 192, 0, stream>>>(T1, T2, statsA, gamma + blk * DIN, beta + blk * DIN, statsB);
      gemm_bn<<<dim3(MT, 3), 256, 0, stream>>>(T2, W2t + (size_t)blk * DP * DP, T1, b2 + blk * DIN, statsB);
      elt_res<<<MT, 192, 0, stream>>>(T1, X, statsB, gamma + blk * DIN, beta + blk * DIN, statsA,
                                      (blk == NBLK - 1) ? fxo : (float*)nullptr);
    }
    fh_mfma<<<dim3(FH_S, 3, BATCH), 256, 0, stream>>>(Eb, X, Fh + (size_t)f * BATCH * KDP * DP);
  }
  gram_kern<<<dim3(3, BATCH), 256, 0, stream>>>(Fh, gram);
  chol_kern<<<16, 256, 0, stream>>>(gram, Lb, invd);
  solve_kern<<<16, 128, 0, stream>>>(Lb, invd, gram, out);
}

// Round 2
// 3538.236 us; speedup vs baseline: 1.1550x; 1.0747x over previous
//
#include <hip/hip_runtime.h>
#include <hip/hip_bf16.h>
#include <stdint.h>
#include <stddef.h>

#define RROWS 55120   // 8*6890 rows
#define DIN   352
#define DP    384     // padded channel dim
#define NBLK  7
#define KD    120     // eigenbasis size
#define KDP   128     // padded
#define BATCH 8
#define NVERT 6890
#define BN_EPS 1e-3f
#define FH_S  16      // split-K chunks for Fh GEMM

typedef __attribute__((ext_vector_type(8))) short short8;
typedef __attribute__((ext_vector_type(4))) float floatx4;

__device__ __forceinline__ short f2bf(float f) {
  union { float f; uint32_t u; } v; v.f = f;
  uint32_t r = (v.u + 0x7fffu + ((v.u >> 16) & 1u)) >> 16;  // RNE
  return (short)r;
}
__device__ __forceinline__ float bf2f(short s) {
  union { uint32_t u; float f; } v; v.u = ((uint32_t)(uint16_t)s) << 16;
  return v.f;
}

// ---------------------------------------------------------------------------
// Weight prep: Wt[blk][n][k] = bf16(W[blk][k][n]), zero-padded 352->384
// ---------------------------------------------------------------------------
__global__ __launch_bounds__(256) void prep_w(const float* __restrict__ W1, const float* __restrict__ W2,
                                              short* __restrict__ W1t, short* __restrict__ W2t) {
  int e = blockIdx.x * 256 + threadIdx.x;
  const float* W = blockIdx.y ? W2 : W1;
  short* Wt = blockIdx.y ? W2t : W1t;
  int blk = e / (DP * DP);
  int rem = e - blk * DP * DP;
  int n = rem / DP;
  int k = rem - n * DP;
  float v = (n < DIN && k < DIN) ? W[(size_t)blk * DIN * DIN + (size_t)k * DIN + n] : 0.f;
  Wt[e] = f2bf(v);
}

// ---------------------------------------------------------------------------
// cast evecs fp32 [b][n][120] -> bf16 [b][n][128] (padded)
// ---------------------------------------------------------------------------
__global__ __launch_bounds__(256) void cast_e(const float* __restrict__ E, short* __restrict__ Eb) {
  int idx = blockIdx.x * 256 + threadIdx.x;
  int u8 = idx & 15;
  int n = idx >> 4;
  if (n >= NVERT) return;
  int b = blockIdx.y;
  short8 o;
  if (u8 < 15) {
    const float* src = E + ((size_t)b * NVERT + n) * KD + u8 * 8;
    #pragma unroll
    for (int j = 0; j < 8; ++j) o[j] = f2bf(src[j]);
  } else {
    #pragma unroll
    for (int j = 0; j < 8; ++j) o[j] = 0;
  }
  *(short8*)(Eb + ((size_t)b * NVERT + n) * KDP + u8 * 8) = o;
}

// ---------------------------------------------------------------------------
// cast input fp32 -> bf16, pad channels to 384; block 0 zeroes statsA
// ---------------------------------------------------------------------------
__global__ __launch_bounds__(192) void cast_in(const float* __restrict__ F, short* __restrict__ X,
                                               float* __restrict__ zbuf) {
  int tid = threadIdx.x;
  if (blockIdx.x == 0)
    for (int z = tid; z < 2 * DP; z += 192) zbuf[z] = 0.f;
  int cg = tid % 48, rl = tid / 48;
  int c0 = cg * 8;
  int row0 = blockIdx.x * 128;
  for (int rr = rl; rr < 128; rr += 4) {
    int row = row0 + rr;
    if (row >= RROWS) break;
    short8 o;
    if (c0 < DIN) {
      const float* src = F + (size_t)row * DIN + c0;
      #pragma unroll
      for (int j = 0; j < 8; ++j) o[j] = f2bf(src[j]);
    } else {
      #pragma unroll
      for (int j = 0; j < 8; ++j) o[j] = 0;
    }
    *(short8*)(X + (size_t)row * DP + c0) = o;
  }
}

// ---------------------------------------------------------------------------
// GEMM: Y[m][n] = A[m][:] @ Wt[n][:] + bias[n]   (bf16 in, bf16 out, fp32 acc)
// fused per-column sum / sumsq atomically into stats
// ---------------------------------------------------------------------------
__global__ __launch_bounds__(256) void gemm_bn(
    const short* __restrict__ A, const short* __restrict__ Bt,
    short* __restrict__ Y, const float* __restrict__ bias,
    float* __restrict__ stats) {
  __shared__ short As[128 * 64];
  __shared__ short Bs[128 * 64];
  const int tid = threadIdx.x;
  const int lane = tid & 63;
  const int w = tid >> 6;
  const int m0 = blockIdx.x * 128;
  const int n0 = blockIdx.y * 128;

  const int rsub = lane >> 3;
  const int gsw = (lane & 7) ^ rsub;

  const short* aSrc[4]; const short* bSrc[4];
  short* aDst[4]; short* bDst[4];
  #pragma unroll
  for (int t = 0; t < 4; ++t) {
    int r = 32 * w + 8 * t + rsub;
    int gm = m0 + r; if (gm >= RROWS) gm = RROWS - 1;
    aSrc[t] = A + (size_t)gm * DP + gsw * 8;
    bSrc[t] = Bt + (size_t)(n0 + r) * DP + gsw * 8;
    aDst[t] = &As[(32 * w + 8 * t) * 64];
    bDst[t] = &Bs[(32 * w + 8 * t) * 64];
  }

  floatx4 acc[4][4];
  #pragma unroll
  for (int i = 0; i < 4; ++i)
    #pragma unroll
    for (int j = 0; j < 4; ++j)
      acc[i][j] = (floatx4){0.f, 0.f, 0.f, 0.f};

  const int l15 = lane & 15;
  const int q = lane >> 4;
  const int wm = 64 * (w >> 1);
  const int wn = 64 * (w & 1);

  for (int kt = 0; kt < DP / 64; ++kt) {
    __syncthreads();
    #pragma unroll
    for (int t = 0; t < 4; ++t) {
      __builtin_amdgcn_global_load_lds((const __attribute__((address_space(1))) void*)(aSrc[t] + kt * 64),
                                       (__attribute__((address_space(3))) void*)aDst[t], 16, 0, 0);
      __builtin_amdgcn_global_load_lds((const __attribute__((address_space(1))) void*)(bSrc[t] + kt * 64),
                                       (__attribute__((address_space(3))) void*)bDst[t], 16, 0, 0);
    }
    __syncthreads();
    #pragma unroll
    for (int ks = 0; ks < 2; ++ks) {
      const int pos8 = ((((ks << 2) | q)) ^ (l15 & 7)) * 8;
      short8 af[4], bfv[4];
      #pragma unroll
      for (int mt = 0; mt < 4; ++mt)
        af[mt] = *(const short8*)&As[(wm + 16 * mt + l15) * 64 + pos8];
      #pragma unroll
      for (int nt = 0; nt < 4; ++nt)
        bfv[nt] = *(const short8*)&Bs[(wn + 16 * nt + l15) * 64 + pos8];
      #pragma unroll
      for (int mt = 0; mt < 4; ++mt)
        #pragma unroll
        for (int nt = 0; nt < 4; ++nt)
          acc[mt][nt] = __builtin_amdgcn_mfma_f32_16x16x32_bf16(af[mt], bfv[nt], acc[mt][nt], 0, 0, 0);
    }
  }

  const int mwb = m0 + wm;
  const int nwb = n0 + wn;
  #pragma unroll
  for (int nt = 0; nt < 4; ++nt) {
    const int n = nwb + 16 * nt + l15;
    const float bv = (n < DIN) ? bias[n] : 0.f;
    float s1 = 0.f, s2 = 0.f;
    #pragma unroll
    for (int mt = 0; mt < 4; ++mt) {
      const int mb = mwb + 16 * mt + 4 * q;
      #pragma unroll
      for (int v = 0; v < 4; ++v) {
        const int m = mb + v;
        if (m < RROWS) {
          float val = acc[mt][nt][v] + bv;
          Y[(size_t)m * DP + n] = f2bf(val);
          s1 += val;
          s2 += val * val;
        }
      }
    }
    s1 += __shfl_xor(s1, 16);
    s2 += __shfl_xor(s2, 16);
    s1 += __shfl_xor(s1, 32);
    s2 += __shfl_xor(s2, 32);
    if (q == 0) {
      atomicAdd(&stats[n], s1);
      atomicAdd(&stats[DP + n], s2);
    }
  }
}

// ---------------------------------------------------------------------------
// ELT1: H = relu(gamma*(Y-mean)*istd + beta); zeroes the other stats buffer
// ---------------------------------------------------------------------------
__global__ __launch_bounds__(192) void elt_bn(
    const short* __restrict__ Yin, short* __restrict__ Hout,
    const float* __restrict__ stats, const float* __restrict__ gamma, const float* __restrict__ beta,
    float* __restrict__ zbuf) {
  int tid = threadIdx.x;
  if (blockIdx.x == 0)
    for (int z = tid; z < 2 * DP; z += 192) zbuf[z] = 0.f;
  int cg = tid % 48, rl = tid / 48;
  int c0 = cg * 8;
  float av[8], bb[8];
  #pragma unroll
  for (int j = 0; j < 8; ++j) {
    int c = c0 + j;
    float mean = stats[c] * (1.f / RROWS);
    float var = stats[DP + c] * (1.f / RROWS) - mean * mean;
    float istd = rsqrtf(var + BN_EPS);
    float g = (c < DIN) ? gamma[c] : 0.f;
    float b = (c < DIN) ? beta[c] : 0.f;
    av[j] = g * istd;
    bb[j] = b - g * istd * mean;
  }
  int row0 = blockIdx.x * 128;
  for (int rr = rl; rr < 128; rr += 4) {
    int row = row0 + rr;
    if (row >= RROWS) break;
    size_t off = (size_t)row * DP + c0;
    short8 y = *(const short8*)(Yin + off);
    short8 h;
    #pragma unroll
    for (int j = 0; j < 8; ++j) {
      float v = av[j] * bf2f(y[j]) + bb[j];
      h[j] = f2bf(fmaxf(v, 0.f));
    }
    *(short8*)(Hout + off) = h;
  }
}

// ---------------------------------------------------------------------------
// ELT2: X = relu(bn(Y) + X); optional fp32 write of result into d_out
// ---------------------------------------------------------------------------
__global__ __launch_bounds__(192) void elt_res(
    const short* __restrict__ Yin, short* __restrict__ X,
    const float* __restrict__ stats, const float* __restrict__ gamma, const float* __restrict__ beta,
    float* __restrict__ zbuf, float* __restrict__ fout) {
  int tid = threadIdx.x;
  if (blockIdx.x == 0)
    for (int z = tid; z < 2 * DP; z += 192) zbuf[z] = 0.f;
  int cg = tid % 48, rl = tid / 48;
  int c0 = cg * 8;
  float av[8], bb[8];
  #pragma unroll
  for (int j = 0; j < 8; ++j) {
    int c = c0 + j;
    float mean = stats[c] * (1.f / RROWS);
    float var = stats[DP + c] * (1.f / RROWS) - mean * mean;
    float istd = rsqrtf(var + BN_EPS);
    float g = (c < DIN) ? gamma[c] : 0.f;
    float b = (c < DIN) ? beta[c] : 0.f;
    av[j] = g * istd;
    bb[j] = b - g * istd * mean;
  }
  int row0 = blockIdx.x * 128;
  for (int rr = rl; rr < 128; rr += 4) {
    int row = row0 + rr;
    if (row >= RROWS) break;
    size_t off = (size_t)row * DP + c0;
    short8 y = *(const short8*)(Yin + off);
    short8 x = *(const short8*)(X + off);
    short8 h;
    float vr[8];
    #pragma unroll
    for (int j = 0; j < 8; ++j) {
      float v = av[j] * bf2f(y[j]) + bb[j] + bf2f(x[j]);
      v = fmaxf(v, 0.f);
      vr[j] = v;
      h[j] = f2bf(v);
    }
    *(short8*)(X + off) = h;
    if (fout != nullptr && c0 < DIN) {
      float4 o0 = make_float4(vr[0], vr[1], vr[2], vr[3]);
      float4 o1 = make_float4(vr[4], vr[5], vr[6], vr[7]);
      *(float4*)(fout + (size_t)row * DIN + c0) = o0;
      *(float4*)(fout + (size_t)row * DIN + c0 + 4) = o1;
    }
  }
}

// ---------------------------------------------------------------------------
// Fh GEMM (bf16 MFMA, split-K, LDS-transpose staging):
//   Fh[u][v] += sum_n E[n][u] * X[n][v]   per batch b
// grid: x = k-chunk (FH_S), y = v-tile (3 of 128), z = batch (8)
// LDS layout [row][72] shorts: 72-pad => ds_read_b128 16B-aligned, <=2-way banks
// ---------------------------------------------------------------------------
__global__ __launch_bounds__(256) void fh_mfma(const short* __restrict__ Eb, const short* __restrict__ X,
                                               float* __restrict__ Fh) {
  __shared__ short Es[128 * 72];
  __shared__ short Xs[128 * 72];
  const int tid = threadIdx.x;
  const int lane = tid & 63;
  const int w = tid >> 6;
  const int b = blockIdx.z;
  const int v0 = blockIdx.y * 128;
  const int chunk = (NVERT + FH_S - 1) / FH_S;  // 431
  const int kbase = blockIdx.x * chunk;
  const int nend = min(kbase + chunk, NVERT);
  const int np = tid & 31;   // n-pair index within 64-tile
  const int ug = tid >> 5;   // 0..7 -> u/v block of 16

  const short* Ebase = Eb + (size_t)b * NVERT * KDP;
  const short* Xbase = X + (size_t)b * NVERT * DP + v0;

  floatx4 acc[4][4];
  #pragma unroll
  for (int i = 0; i < 4; ++i)
    #pragma unroll
    for (int j = 0; j < 4; ++j)
      acc[i][j] = (floatx4){0.f, 0.f, 0.f, 0.f};

  const int l15 = lane & 15;
  const int q = lane >> 4;
  const int wm = 64 * (w >> 1);
  const int wn = 64 * (w & 1);

  const int ntiles = (nend - kbase + 63) >> 6;
  for (int kt = 0; kt < ntiles; ++kt) {
    const int nb = kbase + kt * 64;
    const int n0 = nb + 2 * np;
    const bool ok0 = (n0 < nend);
    const bool ok1 = (n0 + 1 < nend);
    __syncthreads();
    #pragma unroll
    for (int i = 0; i < 2; ++i) {
      const int u0 = ug * 16 + 8 * i;
      short8 z; 
      #pragma unroll
      for (int j = 0; j < 8; ++j) z[j] = 0;
      short8 e0 = z, e1 = z, x0 = z, x1 = z;
      if (ok0) {
        e0 = *(const short8*)(Ebase + (size_t)n0 * KDP + u0);
        x0 = *(const short8*)(Xbase + (size_t)n0 * DP + u0);
      }
      if (ok1) {
        e1 = *(const short8*)(Ebase + (size_t)(n0 + 1) * KDP + u0);
        x1 = *(const short8*)(Xbase + (size_t)(n0 + 1) * DP + u0);
      }
      #pragma unroll
      for (int j = 0; j < 8; ++j) {
        uint32_t ep = (uint32_t)(uint16_t)e0[j] | ((uint32_t)(uint16_t)e1[j] << 16);
        uint32_t xp = (uint32_t)(uint16_t)x0[j] | ((uint32_t)(uint16_t)x1[j] << 16);
        *(uint32_t*)&Es[(u0 + j) * 72 + 2 * np] = ep;
        *(uint32_t*)&Xs[(u0 + j) * 72 + 2 * np] = xp;
      }
    }
    __syncthreads();
    #pragma unroll
    for (int ks = 0; ks < 2; ++ks) {
      const int ko = ks * 32 + q * 8;
      short8 af[4], bfv[4];
      #pragma unroll
      for (int mt = 0; mt < 4; ++mt)
        af[mt] = *(const short8*)&Es[(wm + 16 * mt + l15) * 72 + ko];
      #pragma unroll
      for (int nt = 0; nt < 4; ++nt)
        bfv[nt] = *(const short8*)&Xs[(wn + 16 * nt + l15) * 72 + ko];
      #pragma unroll
      for (int mt = 0; mt < 4; ++mt)
        #pragma unroll
        for (int nt = 0; nt < 4; ++nt)
          acc[mt][nt] = __builtin_amdgcn_mfma_f32_16x16x32_bf16(af[mt], bfv[nt], acc[mt][nt], 0, 0, 0);
    }
  }

  float* Fo = Fh + (size_t)b * (KDP * DP);
  #pragma unroll
  for (int nt = 0; nt < 4; ++nt) {
    const int v = wn + 16 * nt + l15;
    #pragma unroll
    for (int mt = 0; mt < 4; ++mt) {
      const int ub = wm + 16 * mt + 4 * q;
      #pragma unroll
      for (int vi = 0; vi < 4; ++vi) {
        const int u = ub + vi;
        if (u < KD)
          atomicAdd(&Fo[(size_t)u * DP + v0 + v], acc[mt][nt][vi]);
      }
    }
  }
}

// ---------------------------------------------------------------------------
// Gram: mat0=FtF, mat1=FtG, mat2=GtG; Fh rows padded to DP=384 (pad cols are 0)
// ---------------------------------------------------------------------------
__global__ __launch_bounds__(256) void gram_kern(const float* __restrict__ Fh, float* __restrict__ G) {
  __shared__ float As[128 * 33];
  __shared__ float Bs[32 * 132];
  int mat = blockIdx.x, b = blockIdx.y;
  const float* Pa = Fh + (size_t)((mat == 2 ? BATCH : 0) + b) * KDP * DP;
  const float* Pb = Fh + (size_t)((mat == 0 ? 0 : BATCH) + b) * KDP * DP;
  int tid = threadIdx.x;
  int ty = tid >> 4, tx = tid & 15;
  float accv[8][8];
  #pragma unroll
  for (int i = 0; i < 8; ++i)
    #pragma unroll
    for (int j = 0; j < 8; ++j) accv[i][j] = 0.f;
  for (int ch = 0; ch < 12; ++ch) {
    int d0 = ch * 32;
    __syncthreads();
    #pragma unroll
    for (int j = 0; j < 16; ++j) {
      int e = tid + 256 * j;
      int r = e >> 5, c = e & 31;
      float va = (r < KD) ? Pa[(size_t)r * DP + d0 + c] : 0.f;
      float vb = (r < KD) ? Pb[(size_t)r * DP + d0 + c] : 0.f;
      As[r * 33 + c] = va;
      Bs[c * 132 + r] = vb;
    }
    __syncthreads();
    for (int dd = 0; dd < 32; ++dd) {
      float a[8], bv[8];
      #pragma unroll
      for (int i = 0; i < 8; ++i) a[i] = As[(8 * ty + i) * 33 + dd];
      float4 b0 = *(const float4*)&Bs[dd * 132 + 8 * tx];
      float4 b1 = *(const float4*)&Bs[dd * 132 + 8 * tx + 4];
      bv[0] = b0.x; bv[1] = b0.y; bv[2] = b0.z; bv[3] = b0.w;
      bv[4] = b1.x; bv[5] = b1.y; bv[6] = b1.z; bv[7] = b1.w;
      #pragma unroll
      for (int i = 0; i < 8; ++i)
        #pragma unroll
        for (int j = 0; j < 8; ++j)
          accv[i][j] += a[i] * bv[j];
    }
  }
  float* Go = G + (size_t)(b * 3 + mat) * KD * KD;
  #pragma unroll
  for (int i = 0; i < 8; ++i) {
    int k = 8 * ty + i;
    if (k < KD)
      #pragma unroll
      for (int j = 0; j < 8; ++j) {
        int l = 8 * tx + j;
        if (l < KD) Go[k * KD + l] = accv[i][j];
      }
  }
}

// ---------------------------------------------------------------------------
// Fused Cholesky + triangular solves, one block per system (16 systems).
// LDS: Ls (L factor, 58KB) + xs (RHS/solution 120x128, 61KB) ~ 118KiB.
// Chol: element-parallel rank-1 trailing update (verified round-1 logic,
// restrided to 512 threads), diagonal deferred to diag[]/ivs[].
// Solve: RIGHT-looking substitution — after x[k] is known, the rank-1 update
// r[i] -= L[i][k]*x[k] over (rows>k)x(128 cols) is spread across 512 threads
// (16 row-groups x 32 float4-column-quads): one barrier per pivot instead of
// the old serial 60-deep LDS-RMW dot-product chain (375us -> ~target 100us).
// Rows stay unscaled residuals; iv scaling is applied on consumption (v),
// in the mid-pass (fwd->bwd handoff), and at the final output write.
// ---------------------------------------------------------------------------
__global__ __launch_bounds__(512) void chol_solve(const float* __restrict__ G, float* __restrict__ out) {
  __shared__ float Ls[120 * 121];
  __shared__ float xs[120 * 128];
  __shared__ float diag[KD];
  __shared__ float colv[KD];
  __shared__ float ivs[KD];
  const int sys = blockIdx.x;
  const int b = sys >> 1;
  const int which = sys & 1;
  const int mat = which ? 2 : 0;
  const float* Gm = G + (size_t)(b * 3 + mat) * KD * KD;   // FtF or GtG
  const float* Bm = G + (size_t)(b * 3 + 1) * KD * KD;     // FtG (transposed read for which==1)
  const int tid = threadIdx.x;

  // load A into Ls and RHS into xs
  for (int e = tid; e < KD * KD; e += 512) {
    int r = e / KD, c = e - r * KD;
    Ls[r * 121 + c] = Gm[e];
  }
  {
    int t = tid & 127, g = tid >> 7;
    for (int k = g; k < KD; k += 4)
      xs[k * 128 + t] = (t < KD) ? (which == 0 ? Bm[k * KD + t] : Bm[t * KD + k]) : 0.f;
  }
  __syncthreads();

  // ---- Cholesky (diagonal deferred; Ls diag holds running residual) ----
  for (int p = 0; p < KD; ++p) {
    float d = Ls[p * 121 + p];
    float s = sqrtf(d);
    float dinv = 1.f / s;
    if (tid == 0) diag[p] = s;
    for (int i = p + 1 + tid; i < KD; i += 512) {
      float v = Ls[i * 121 + p] * dinv;
      Ls[i * 121 + p] = v;
      colv[i] = v;
    }
    __syncthreads();
    int m = KD - 1 - p;
    int tot = (m * (m + 1)) >> 1;
    for (int e = tid; e < tot; e += 512) {
      int r = (int)((sqrtf(8.f * (float)e + 1.f) - 1.f) * 0.5f);
      int base = (r * (r + 1)) >> 1;
      if (base > e) { base -= r; --r; }
      else if (e - base > r) { ++r; base += r; }
      int i = p + 1 + r;
      int j = p + 1 + (e - base);
      Ls[i * 121 + j] -= colv[i] * colv[j];
    }
    __syncthreads();
  }
  if (tid < KD) ivs[tid] = 1.f / diag[tid];
  __syncthreads();

  // ---- solves: 32 column-quads (float4) x 16 row-groups ----
  const int cq = tid & 31;   // column quad: cols 4*cq..4*cq+3
  const int g = tid >> 5;    // row group 0..15
  const int co = 4 * cq;

  // forward: L y = B  (xs holds unscaled residuals)
  for (int k = 0; k < KD; ++k) {
    __syncthreads();
    float ivk = ivs[k];
    float4 v = *(const float4*)&xs[k * 128 + co];
    v.x *= ivk; v.y *= ivk; v.z *= ivk; v.w *= ivk;
    for (int i = k + 1 + g; i < KD; i += 16) {
      float lik = Ls[i * 121 + k];
      float4* p4 = (float4*)&xs[i * 128 + co];
      float4 x = *p4;
      x.x -= lik * v.x; x.y -= lik * v.y; x.z -= lik * v.z; x.w -= lik * v.w;
      *p4 = x;
    }
  }
  // mid-pass: y = resid * iv  (handoff to backward solve)
  __syncthreads();
  for (int i = g; i < KD; i += 16) {
    float ivi = ivs[i];
    float4* p4 = (float4*)&xs[i * 128 + co];
    float4 x = *p4;
    x.x *= ivi; x.y *= ivi; x.z *= ivi; x.w *= ivi;
    *p4 = x;
  }
  // backward: L^T x = y
  for (int k = KD - 1; k > 0; --k) {
    __syncthreads();
    float ivk = ivs[k];
    float4 v = *(const float4*)&xs[k * 128 + co];
    v.x *= ivk; v.y *= ivk; v.z *= ivk; v.w *= ivk;
    for (int i = g; i < k; i += 16) {
      float lki = Ls[k * 121 + i];
      float4* p4 = (float4*)&xs[i * 128 + co];
      float4 x = *p4;
      x.x -= lki * v.x; x.y -= lki * v.y; x.z -= lki * v.z; x.w -= lki * v.w;
      *p4 = x;
    }
  }
  __syncthreads();

  // output: Co[t][k] = xs[k][t] * iv[k]   (final backward scaling folded in)
  float* Co = out + (size_t)which * BATCH * KD * KD + (size_t)b * KD * KD;
  {
    int t = tid & 127, gg = tid >> 7;
    if (t < KD)
      for (int k = gg; k < KD; k += 4)
        Co[(size_t)t * KD + k] = xs[k * 128 + t] * ivs[k];
  }
}

// ---------------------------------------------------------------------------
extern "C" void kernel_launch(void* const* d_in, const int* in_sizes, int n_in,
                              void* d_out, int out_size, void* d_ws, size_t ws_size,
                              hipStream_t stream) {
  (void)in_sizes; (void)n_in; (void)out_size; (void)ws_size;
  const float* feat_x = (const float*)d_in[0];
  const float* feat_y = (const float*)d_in[1];
  const float* evecs_x = (const float*)d_in[2];
  const float* evecs_y = (const float*)d_in[3];
  const float* W1 = (const float*)d_in[4];
  const float* b1 = (const float*)d_in[5];
  const float* W2 = (const float*)d_in[6];
  const float* b2 = (const float*)d_in[7];
  const float* gamma = (const float*)d_in[8];
  const float* beta = (const float*)d_in[9];
  float* out = (float*)d_out;

  char* p = (char*)d_ws;
  auto carve = [&](size_t bytes) { char* r = p; p += (bytes + 255) & ~(size_t)255; return r; };
  short* W1t = (short*)carve(7ull * DP * DP * 2);
  short* W2t = (short*)carve(7ull * DP * DP * 2);
  short* X  = (short*)carve((size_t)RROWS * DP * 2);
  short* T1 = (short*)carve((size_t)RROWS * DP * 2);
  short* T2 = (short*)carve((size_t)RROWS * DP * 2);
  short* Eb = (short*)carve((size_t)BATCH * NVERT * KDP * 2);
  float* stats = (float*)carve(4ull * DP * 4);
  float* Fh = (float*)carve(2ull * BATCH * KDP * DP * 4);
  float* gram = (float*)carve((size_t)BATCH * 3 * KD * KD * 4);
  float* statsA = stats;
  float* statsB = stats + 2 * DP;

  hipMemsetAsync(Fh, 0, 2ull * BATCH * KDP * DP * 4, stream);
  prep_w<<<dim3((7 * DP * DP) / 256, 2), 256, 0, stream>>>(W1, W2, W1t, W2t);

  const int MT = (RROWS + 127) / 128;  // 431
  const int ET = (NVERT * 16 + 255) / 256;  // 431
  for (int f = 0; f < 2; ++f) {
    const float* feat = f ? feat_y : feat_x;
    const float* ev = f ? evecs_y : evecs_x;
    float* fxo = out + 2 * BATCH * KD * KD + (size_t)f * RROWS * DIN;
    cast_in<<<MT, 192, 0, stream>>>(feat, X, statsA);
    cast_e<<<dim3(ET, BATCH), 256, 0, stream>>>(ev, Eb);
    for (int blk = 0; blk < NBLK; ++blk) {
      gemm_bn<<<dim3(MT, 3), 256, 0, stream>>>(X, W1t + (size_t)blk * DP * DP, T1, b1 + blk * DIN, statsA);
      elt_bn<<<MT, 192, 0, stream>>>(T1, T2, statsA, gamma + blk * DIN, beta + blk * DIN, statsB);
      gemm_bn<<<dim3(MT, 3), 256, 0, stream>>>(T2, W2t + (size_t)blk * DP * DP, T1, b2 + blk * DIN, statsB);
      elt_res<<<MT, 192, 0, stream>>>(T1, X, statsB, gamma + blk * DIN, beta + blk * DIN, statsA,
                                      (blk == NBLK - 1) ? fxo : (float*)nullptr);
    }
    fh_mfma<<<dim3(FH_S, 3, BATCH), 256, 0, stream>>>(Eb, X, Fh + (size_t)f * BATCH * KDP * DP);
  }
  gram_kern<<<dim3(3, BATCH), 256, 0, stream>>>(Fh, gram);
  chol_solve<<<16, 512, 0, stream>>>(gram, out);
}

// Round 3
// 3248.286 us; speedup vs baseline: 1.2581x; 1.0893x over previous
//
#include <hip/hip_runtime.h>
#include <hip/hip_bf16.h>
#include <stdint.h>
#include <stddef.h>

#define RROWS 55120   // 8*6890 rows
#define DIN   352
#define DP    384     // padded channel dim
#define NBLK  7
#define KD    120     // eigenbasis size
#define KDP   128     // padded
#define BATCH 8
#define NVERT 6890
#define BN_EPS 1e-3f
#define FH_S  16      // split-K chunks for Fh GEMM
#define NB    8       // chol/solve panel width
#define NSTEP (KD / NB)

typedef __attribute__((ext_vector_type(8))) short short8;
typedef __attribute__((ext_vector_type(4))) float floatx4;

__device__ __forceinline__ short f2bf(float f) {
  union { float f; uint32_t u; } v; v.f = f;
  uint32_t r = (v.u + 0x7fffu + ((v.u >> 16) & 1u)) >> 16;  // RNE
  return (short)r;
}
__device__ __forceinline__ float bf2f(short s) {
  union { uint32_t u; float f; } v; v.u = ((uint32_t)(uint16_t)s) << 16;
  return v.f;
}

// ---------------------------------------------------------------------------
// Weight prep: Wt[blk][n][k] = bf16(W[blk][k][n]), zero-padded 352->384
// ---------------------------------------------------------------------------
__global__ __launch_bounds__(256) void prep_w(const float* __restrict__ W1, const float* __restrict__ W2,
                                              short* __restrict__ W1t, short* __restrict__ W2t) {
  int e = blockIdx.x * 256 + threadIdx.x;
  const float* W = blockIdx.y ? W2 : W1;
  short* Wt = blockIdx.y ? W2t : W1t;
  int blk = e / (DP * DP);
  int rem = e - blk * DP * DP;
  int n = rem / DP;
  int k = rem - n * DP;
  float v = (n < DIN && k < DIN) ? W[(size_t)blk * DIN * DIN + (size_t)k * DIN + n] : 0.f;
  Wt[e] = f2bf(v);
}

// ---------------------------------------------------------------------------
// cast evecs fp32 [b][n][120] -> bf16 [b][n][128] (padded)
// ---------------------------------------------------------------------------
__global__ __launch_bounds__(256) void cast_e(const float* __restrict__ E, short* __restrict__ Eb) {
  int idx = blockIdx.x * 256 + threadIdx.x;
  int u8 = idx & 15;
  int n = idx >> 4;
  if (n >= NVERT) return;
  int b = blockIdx.y;
  short8 o;
  if (u8 < 15) {
    const float* src = E + ((size_t)b * NVERT + n) * KD + u8 * 8;
    #pragma unroll
    for (int j = 0; j < 8; ++j) o[j] = f2bf(src[j]);
  } else {
    #pragma unroll
    for (int j = 0; j < 8; ++j) o[j] = 0;
  }
  *(short8*)(Eb + ((size_t)b * NVERT + n) * KDP + u8 * 8) = o;
}

// ---------------------------------------------------------------------------
// cast input fp32 -> bf16, pad channels to 384; block 0 zeroes statsA
// ---------------------------------------------------------------------------
__global__ __launch_bounds__(192) void cast_in(const float* __restrict__ F, short* __restrict__ X,
                                               float* __restrict__ zbuf) {
  int tid = threadIdx.x;
  if (blockIdx.x == 0)
    for (int z = tid; z < 2 * DP; z += 192) zbuf[z] = 0.f;
  int cg = tid % 48, rl = tid / 48;
  int c0 = cg * 8;
  int row0 = blockIdx.x * 128;
  for (int rr = rl; rr < 128; rr += 4) {
    int row = row0 + rr;
    if (row >= RROWS) break;
    short8 o;
    if (c0 < DIN) {
      const float* src = F + (size_t)row * DIN + c0;
      #pragma unroll
      for (int j = 0; j < 8; ++j) o[j] = f2bf(src[j]);
    } else {
      #pragma unroll
      for (int j = 0; j < 8; ++j) o[j] = 0;
    }
    *(short8*)(X + (size_t)row * DP + c0) = o;
  }
}

// ---------------------------------------------------------------------------
// GEMM: Y[m][n] = A[m][:] @ Wt[n][:] + bias[n]   (bf16 in, bf16 out, fp32 acc)
// fused per-column sum / sumsq atomically into stats; block(0,0) zeroes zb
// (the stats buffer the NEXT gemm will accumulate into — idle during this one)
// ---------------------------------------------------------------------------
__global__ __launch_bounds__(256) void gemm_bn(
    const short* __restrict__ A, const short* __restrict__ Bt,
    short* __restrict__ Y, const float* __restrict__ bias,
    float* __restrict__ stats, float* __restrict__ zb) {
  __shared__ short As[128 * 64];
  __shared__ short Bs[128 * 64];
  const int tid = threadIdx.x;
  const int lane = tid & 63;
  const int w = tid >> 6;
  const int m0 = blockIdx.x * 128;
  const int n0 = blockIdx.y * 128;

  if (blockIdx.x == 0 && blockIdx.y == 0)
    for (int z = tid; z < 2 * DP; z += 256) zb[z] = 0.f;

  const int rsub = lane >> 3;
  const int gsw = (lane & 7) ^ rsub;

  const short* aSrc[4]; const short* bSrc[4];
  short* aDst[4]; short* bDst[4];
  #pragma unroll
  for (int t = 0; t < 4; ++t) {
    int r = 32 * w + 8 * t + rsub;
    int gm = m0 + r; if (gm >= RROWS) gm = RROWS - 1;
    aSrc[t] = A + (size_t)gm * DP + gsw * 8;
    bSrc[t] = Bt + (size_t)(n0 + r) * DP + gsw * 8;
    aDst[t] = &As[(32 * w + 8 * t) * 64];
    bDst[t] = &Bs[(32 * w + 8 * t) * 64];
  }

  floatx4 acc[4][4];
  #pragma unroll
  for (int i = 0; i < 4; ++i)
    #pragma unroll
    for (int j = 0; j < 4; ++j)
      acc[i][j] = (floatx4){0.f, 0.f, 0.f, 0.f};

  const int l15 = lane & 15;
  const int q = lane >> 4;
  const int wm = 64 * (w >> 1);
  const int wn = 64 * (w & 1);

  for (int kt = 0; kt < DP / 64; ++kt) {
    __syncthreads();
    #pragma unroll
    for (int t = 0; t < 4; ++t) {
      __builtin_amdgcn_global_load_lds((const __attribute__((address_space(1))) void*)(aSrc[t] + kt * 64),
                                       (__attribute__((address_space(3))) void*)aDst[t], 16, 0, 0);
      __builtin_amdgcn_global_load_lds((const __attribute__((address_space(1))) void*)(bSrc[t] + kt * 64),
                                       (__attribute__((address_space(3))) void*)bDst[t], 16, 0, 0);
    }
    __syncthreads();
    #pragma unroll
    for (int ks = 0; ks < 2; ++ks) {
      const int pos8 = ((((ks << 2) | q)) ^ (l15 & 7)) * 8;
      short8 af[4], bfv[4];
      #pragma unroll
      for (int mt = 0; mt < 4; ++mt)
        af[mt] = *(const short8*)&As[(wm + 16 * mt + l15) * 64 + pos8];
      #pragma unroll
      for (int nt = 0; nt < 4; ++nt)
        bfv[nt] = *(const short8*)&Bs[(wn + 16 * nt + l15) * 64 + pos8];
      #pragma unroll
      for (int mt = 0; mt < 4; ++mt)
        #pragma unroll
        for (int nt = 0; nt < 4; ++nt)
          acc[mt][nt] = __builtin_amdgcn_mfma_f32_16x16x32_bf16(af[mt], bfv[nt], acc[mt][nt], 0, 0, 0);
    }
  }

  const int mwb = m0 + wm;
  const int nwb = n0 + wn;
  #pragma unroll
  for (int nt = 0; nt < 4; ++nt) {
    const int n = nwb + 16 * nt + l15;
    const float bv = (n < DIN) ? bias[n] : 0.f;
    float s1 = 0.f, s2 = 0.f;
    #pragma unroll
    for (int mt = 0; mt < 4; ++mt) {
      const int mb = mwb + 16 * mt + 4 * q;
      #pragma unroll
      for (int v = 0; v < 4; ++v) {
        const int m = mb + v;
        if (m < RROWS) {
          float val = acc[mt][nt][v] + bv;
          Y[(size_t)m * DP + n] = f2bf(val);
          s1 += val;
          s2 += val * val;
        }
      }
    }
    s1 += __shfl_xor(s1, 16);
    s2 += __shfl_xor(s2, 16);
    s1 += __shfl_xor(s1, 32);
    s2 += __shfl_xor(s2, 32);
    if (q == 0) {
      atomicAdd(&stats[n], s1);
      atomicAdd(&stats[DP + n], s2);
    }
  }
}

// ---------------------------------------------------------------------------
// Fused elt_bn + GEMM: A-operand = relu(av*bf2f(Ain)+bb) computed in-flight
// during reg-staged A load (affine table in LDS from pstats). B via gload_lds.
// Numerically identical to old elt_bn->gemm path (same bf16 rounding points).
// ---------------------------------------------------------------------------
__global__ __launch_bounds__(256) void gemm_bn_f(
    const short* __restrict__ A, const short* __restrict__ Bt,
    short* __restrict__ Y, const float* __restrict__ bias,
    float* __restrict__ stats, const float* __restrict__ pstats,
    const float* __restrict__ gamma, const float* __restrict__ beta) {
  __shared__ short As[128 * 64];
  __shared__ short Bs[128 * 64];
  __shared__ float avs[DP];
  __shared__ float bbs[DP];
  const int tid = threadIdx.x;
  const int lane = tid & 63;
  const int w = tid >> 6;
  const int m0 = blockIdx.x * 128;
  const int n0 = blockIdx.y * 128;

  // affine table from producer stats
  for (int c = tid; c < DP; c += 256) {
    float mean = pstats[c] * (1.f / RROWS);
    float var = pstats[DP + c] * (1.f / RROWS) - mean * mean;
    float istd = rsqrtf(var + BN_EPS);
    float g = (c < DIN) ? gamma[c] : 0.f;
    float b = (c < DIN) ? beta[c] : 0.f;
    avs[c] = g * istd;
    bbs[c] = b - g * istd * mean;
  }

  const int rsub = lane >> 3;
  const int gsw = (lane & 7) ^ rsub;

  const short* aSrc[4]; const short* bSrc[4];
  short* bDst[4];
  #pragma unroll
  for (int t = 0; t < 4; ++t) {
    int r = 32 * w + 8 * t + rsub;
    int gm = m0 + r; if (gm >= RROWS) gm = RROWS - 1;
    aSrc[t] = A + (size_t)gm * DP + gsw * 8;
    bSrc[t] = Bt + (size_t)(n0 + r) * DP + gsw * 8;
    bDst[t] = &Bs[(32 * w + 8 * t) * 64];
  }

  floatx4 acc[4][4];
  #pragma unroll
  for (int i = 0; i < 4; ++i)
    #pragma unroll
    for (int j = 0; j < 4; ++j)
      acc[i][j] = (floatx4){0.f, 0.f, 0.f, 0.f};

  const int l15 = lane & 15;
  const int q = lane >> 4;
  const int wm = 64 * (w >> 1);
  const int wn = 64 * (w & 1);

  for (int kt = 0; kt < DP / 64; ++kt) {
    __syncthreads();   // also covers the affine-table build on first pass
    // B tile via async gload_lds (same swizzle as before)
    #pragma unroll
    for (int t = 0; t < 4; ++t)
      __builtin_amdgcn_global_load_lds((const __attribute__((address_space(1))) void*)(bSrc[t] + kt * 64),
                                       (__attribute__((address_space(3))) void*)bDst[t], 16, 0, 0);
    // A tile: reg-staged, affine+relu applied, written in identical layout
    {
      const int ch0 = kt * 64 + gsw * 8;
      float4 a0 = *(const float4*)&avs[ch0];
      float4 a1 = *(const float4*)&avs[ch0 + 4];
      float4 c0 = *(const float4*)&bbs[ch0];
      float4 c1 = *(const float4*)&bbs[ch0 + 4];
      float av8[8] = {a0.x, a0.y, a0.z, a0.w, a1.x, a1.y, a1.z, a1.w};
      float bb8[8] = {c0.x, c0.y, c0.z, c0.w, c1.x, c1.y, c1.z, c1.w};
      short8 ya[4];
      #pragma unroll
      for (int t = 0; t < 4; ++t) ya[t] = *(const short8*)(aSrc[t] + kt * 64);
      #pragma unroll
      for (int t = 0; t < 4; ++t) {
        short8 h;
        #pragma unroll
        for (int j = 0; j < 8; ++j) {
          float v = av8[j] * bf2f(ya[t][j]) + bb8[j];
          h[j] = f2bf(fmaxf(v, 0.f));
        }
        *(short8*)&As[(32 * w + 8 * t + rsub) * 64 + (lane & 7) * 8] = h;
      }
    }
    __syncthreads();
    #pragma unroll
    for (int ks = 0; ks < 2; ++ks) {
      const int pos8 = ((((ks << 2) | q)) ^ (l15 & 7)) * 8;
      short8 af[4], bfv[4];
      #pragma unroll
      for (int mt = 0; mt < 4; ++mt)
        af[mt] = *(const short8*)&As[(wm + 16 * mt + l15) * 64 + pos8];
      #pragma unroll
      for (int nt = 0; nt < 4; ++nt)
        bfv[nt] = *(const short8*)&Bs[(wn + 16 * nt + l15) * 64 + pos8];
      #pragma unroll
      for (int mt = 0; mt < 4; ++mt)
        #pragma unroll
        for (int nt = 0; nt < 4; ++nt)
          acc[mt][nt] = __builtin_amdgcn_mfma_f32_16x16x32_bf16(af[mt], bfv[nt], acc[mt][nt], 0, 0, 0);
    }
  }

  const int mwb = m0 + wm;
  const int nwb = n0 + wn;
  #pragma unroll
  for (int nt = 0; nt < 4; ++nt) {
    const int n = nwb + 16 * nt + l15;
    const float bv = (n < DIN) ? bias[n] : 0.f;
    float s1 = 0.f, s2 = 0.f;
    #pragma unroll
    for (int mt = 0; mt < 4; ++mt) {
      const int mb = mwb + 16 * mt + 4 * q;
      #pragma unroll
      for (int v = 0; v < 4; ++v) {
        const int m = mb + v;
        if (m < RROWS) {
          float val = acc[mt][nt][v] + bv;
          Y[(size_t)m * DP + n] = f2bf(val);
          s1 += val;
          s2 += val * val;
        }
      }
    }
    s1 += __shfl_xor(s1, 16);
    s2 += __shfl_xor(s2, 16);
    s1 += __shfl_xor(s1, 32);
    s2 += __shfl_xor(s2, 32);
    if (q == 0) {
      atomicAdd(&stats[n], s1);
      atomicAdd(&stats[DP + n], s2);
    }
  }
}

// ---------------------------------------------------------------------------
// ELT2: X = relu(bn(Y) + X); optional fp32 write of result into d_out
// ---------------------------------------------------------------------------
__global__ __launch_bounds__(192) void elt_res(
    const short* __restrict__ Yin, short* __restrict__ X,
    const float* __restrict__ stats, const float* __restrict__ gamma, const float* __restrict__ beta,
    float* __restrict__ zbuf, float* __restrict__ fout) {
  int tid = threadIdx.x;
  if (blockIdx.x == 0)
    for (int z = tid; z < 2 * DP; z += 192) zbuf[z] = 0.f;
  int cg = tid % 48, rl = tid / 48;
  int c0 = cg * 8;
  float av[8], bb[8];
  #pragma unroll
  for (int j = 0; j < 8; ++j) {
    int c = c0 + j;
    float mean = stats[c] * (1.f / RROWS);
    float var = stats[DP + c] * (1.f / RROWS) - mean * mean;
    float istd = rsqrtf(var + BN_EPS);
    float g = (c < DIN) ? gamma[c] : 0.f;
    float b = (c < DIN) ? beta[c] : 0.f;
    av[j] = g * istd;
    bb[j] = b - g * istd * mean;
  }
  int row0 = blockIdx.x * 128;
  for (int rr = rl; rr < 128; rr += 4) {
    int row = row0 + rr;
    if (row >= RROWS) break;
    size_t off = (size_t)row * DP + c0;
    short8 y = *(const short8*)(Yin + off);
    short8 x = *(const short8*)(X + off);
    short8 h;
    float vr[8];
    #pragma unroll
    for (int j = 0; j < 8; ++j) {
      float v = av[j] * bf2f(y[j]) + bb[j] + bf2f(x[j]);
      v = fmaxf(v, 0.f);
      vr[j] = v;
      h[j] = f2bf(v);
    }
    *(short8*)(X + off) = h;
    if (fout != nullptr && c0 < DIN) {
      float4 o0 = make_float4(vr[0], vr[1], vr[2], vr[3]);
      float4 o1 = make_float4(vr[4], vr[5], vr[6], vr[7]);
      *(float4*)(fout + (size_t)row * DIN + c0) = o0;
      *(float4*)(fout + (size_t)row * DIN + c0 + 4) = o1;
    }
  }
}

// ---------------------------------------------------------------------------
// Fh GEMM (bf16 MFMA, split-K, LDS-transpose staging):
//   Fh[u][v] += sum_n E[n][u] * X[n][v]   per batch b
// ---------------------------------------------------------------------------
__global__ __launch_bounds__(256) void fh_mfma(const short* __restrict__ Eb, const short* __restrict__ X,
                                               float* __restrict__ Fh) {
  __shared__ short Es[128 * 72];
  __shared__ short Xs[128 * 72];
  const int tid = threadIdx.x;
  const int lane = tid & 63;
  const int w = tid >> 6;
  const int b = blockIdx.z;
  const int v0 = blockIdx.y * 128;
  const int chunk = (NVERT + FH_S - 1) / FH_S;  // 431
  const int kbase = blockIdx.x * chunk;
  const int nend = min(kbase + chunk, NVERT);
  const int np = tid & 31;
  const int ug = tid >> 5;

  const short* Ebase = Eb + (size_t)b * NVERT * KDP;
  const short* Xbase = X + (size_t)b * NVERT * DP + v0;

  floatx4 acc[4][4];
  #pragma unroll
  for (int i = 0; i < 4; ++i)
    #pragma unroll
    for (int j = 0; j < 4; ++j)
      acc[i][j] = (floatx4){0.f, 0.f, 0.f, 0.f};

  const int l15 = lane & 15;
  const int q = lane >> 4;
  const int wm = 64 * (w >> 1);
  const int wn = 64 * (w & 1);

  const int ntiles = (nend - kbase + 63) >> 6;
  for (int kt = 0; kt < ntiles; ++kt) {
    const int nb = kbase + kt * 64;
    const int n0 = nb + 2 * np;
    const bool ok0 = (n0 < nend);
    const bool ok1 = (n0 + 1 < nend);
    __syncthreads();
    #pragma unroll
    for (int i = 0; i < 2; ++i) {
      const int u0 = ug * 16 + 8 * i;
      short8 z;
      #pragma unroll
      for (int j = 0; j < 8; ++j) z[j] = 0;
      short8 e0 = z, e1 = z, x0 = z, x1 = z;
      if (ok0) {
        e0 = *(const short8*)(Ebase + (size_t)n0 * KDP + u0);
        x0 = *(const short8*)(Xbase + (size_t)n0 * DP + u0);
      }
      if (ok1) {
        e1 = *(const short8*)(Ebase + (size_t)(n0 + 1) * KDP + u0);
        x1 = *(const short8*)(Xbase + (size_t)(n0 + 1) * DP + u0);
      }
      #pragma unroll
      for (int j = 0; j < 8; ++j) {
        uint32_t ep = (uint32_t)(uint16_t)e0[j] | ((uint32_t)(uint16_t)e1[j] << 16);
        uint32_t xp = (uint32_t)(uint16_t)x0[j] | ((uint32_t)(uint16_t)x1[j] << 16);
        *(uint32_t*)&Es[(u0 + j) * 72 + 2 * np] = ep;
        *(uint32_t*)&Xs[(u0 + j) * 72 + 2 * np] = xp;
      }
    }
    __syncthreads();
    #pragma unroll
    for (int ks = 0; ks < 2; ++ks) {
      const int ko = ks * 32 + q * 8;
      short8 af[4], bfv[4];
      #pragma unroll
      for (int mt = 0; mt < 4; ++mt)
        af[mt] = *(const short8*)&Es[(wm + 16 * mt + l15) * 72 + ko];
      #pragma unroll
      for (int nt = 0; nt < 4; ++nt)
        bfv[nt] = *(const short8*)&Xs[(wn + 16 * nt + l15) * 72 + ko];
      #pragma unroll
      for (int mt = 0; mt < 4; ++mt)
        #pragma unroll
        for (int nt = 0; nt < 4; ++nt)
          acc[mt][nt] = __builtin_amdgcn_mfma_f32_16x16x32_bf16(af[mt], bfv[nt], acc[mt][nt], 0, 0, 0);
    }
  }

  float* Fo = Fh + (size_t)b * (KDP * DP);
  #pragma unroll
  for (int nt = 0; nt < 4; ++nt) {
    const int v = wn + 16 * nt + l15;
    #pragma unroll
    for (int mt = 0; mt < 4; ++mt) {
      const int ub = wm + 16 * mt + 4 * q;
      #pragma unroll
      for (int vi = 0; vi < 4; ++vi) {
        const int u = ub + vi;
        if (u < KD)
          atomicAdd(&Fo[(size_t)u * DP + v0 + v], acc[mt][nt][vi]);
      }
    }
  }
}

// ---------------------------------------------------------------------------
// Gram: mat0=FtF, mat1=FtG, mat2=GtG
// ---------------------------------------------------------------------------
__global__ __launch_bounds__(256) void gram_kern(const float* __restrict__ Fh, float* __restrict__ G) {
  __shared__ float As[128 * 33];
  __shared__ float Bs[32 * 132];
  int mat = blockIdx.x, b = blockIdx.y;
  const float* Pa = Fh + (size_t)((mat == 2 ? BATCH : 0) + b) * KDP * DP;
  const float* Pb = Fh + (size_t)((mat == 0 ? 0 : BATCH) + b) * KDP * DP;
  int tid = threadIdx.x;
  int ty = tid >> 4, tx = tid & 15;
  float accv[8][8];
  #pragma unroll
  for (int i = 0; i < 8; ++i)
    #pragma unroll
    for (int j = 0; j < 8; ++j) accv[i][j] = 0.f;
  for (int ch = 0; ch < 12; ++ch) {
    int d0 = ch * 32;
    __syncthreads();
    #pragma unroll
    for (int j = 0; j < 16; ++j) {
      int e = tid + 256 * j;
      int r = e >> 5, c = e & 31;
      float va = (r < KD) ? Pa[(size_t)r * DP + d0 + c] : 0.f;
      float vb = (r < KD) ? Pb[(size_t)r * DP + d0 + c] : 0.f;
      As[r * 33 + c] = va;
      Bs[c * 132 + r] = vb;
    }
    __syncthreads();
    for (int dd = 0; dd < 32; ++dd) {
      float a[8], bv[8];
      #pragma unroll
      for (int i = 0; i < 8; ++i) a[i] = As[(8 * ty + i) * 33 + dd];
      float4 b0 = *(const float4*)&Bs[dd * 132 + 8 * tx];
      float4 b1 = *(const float4*)&Bs[dd * 132 + 8 * tx + 4];
      bv[0] = b0.x; bv[1] = b0.y; bv[2] = b0.z; bv[3] = b0.w;
      bv[4] = b1.x; bv[5] = b1.y; bv[6] = b1.z; bv[7] = b1.w;
      #pragma unroll
      for (int i = 0; i < 8; ++i)
        #pragma unroll
        for (int j = 0; j < 8; ++j)
          accv[i][j] += a[i] * bv[j];
    }
  }
  float* Go = G + (size_t)(b * 3 + mat) * KD * KD;
  #pragma unroll
  for (int i = 0; i < 8; ++i) {
    int k = 8 * ty + i;
    if (k < KD)
      #pragma unroll
      for (int j = 0; j < 8; ++j) {
        int l = 8 * tx + j;
        if (l < KD) Go[k * KD + l] = accv[i][j];
      }
  }
}

// ---------------------------------------------------------------------------
// Fused BLOCKED Cholesky + triangular solves (NB=8 panels, 15 steps each).
// Replaces the 480 per-pivot barrier iterations (latency-bound, 257us) with
// 90 panel steps: every thread redundantly factors the 8x8 diag block in regs
// (broadcast LDS reads, no extra barrier), panel rows are one-thread-per-row,
// and the rank-8 trailing / solve updates amortize 8 FMAs per LDS RMW.
// Ls stride 121 (odd) keeps scalar row accesses spread across all 32 banks.
// ---------------------------------------------------------------------------
__global__ __launch_bounds__(512) void chol_solve(const float* __restrict__ G, float* __restrict__ out) {
  __shared__ float Ls[KD * 121];
  __shared__ float xs[KD * 128];
  __shared__ float ivs[KD];
  const int sys = blockIdx.x;
  const int b = sys >> 1;
  const int which = sys & 1;
  const int mat = which ? 2 : 0;
  const float* Gm = G + (size_t)(b * 3 + mat) * KD * KD;   // FtF or GtG
  const float* Bm = G + (size_t)(b * 3 + 1) * KD * KD;     // FtG
  const int tid = threadIdx.x;

  for (int e = tid; e < KD * KD; e += 512) {
    int r = e / KD, c = e - r * KD;
    Ls[r * 121 + c] = Gm[e];
  }
  {
    int t = tid & 127, g4 = tid >> 7;
    for (int k = g4; k < KD; k += 4)
      xs[k * 128 + t] = (t < KD) ? (which == 0 ? Bm[k * KD + t] : Bm[t * KD + k]) : 0.f;
  }
  __syncthreads();

  // ---------------- blocked Cholesky ----------------
  for (int kb = 0; kb < NSTEP; ++kb) {
    const int k0 = kb * NB;
    const int m = KD - k0 - NB;   // panel / trailing rows

    // phase 1: every thread factors the 8x8 diag block redundantly (regs);
    //          panel threads solve their row against it.
    float D[NB][NB];
    #pragma unroll
    for (int i = 0; i < NB; ++i)
      #pragma unroll
      for (int j = 0; j <= i; ++j)
        D[i][j] = Ls[(k0 + i) * 121 + k0 + j];
    float di[NB];
    #pragma unroll
    for (int j = 0; j < NB; ++j) {
      float s = sqrtf(D[j][j]);
      float inv = 1.f / s;
      D[j][j] = s; di[j] = inv;
      #pragma unroll
      for (int i = j + 1; i < NB; ++i) D[i][j] *= inv;
      #pragma unroll
      for (int i = j + 1; i < NB; ++i)
        #pragma unroll
        for (int c = j + 1; c <= i; ++c)
          D[i][c] -= D[i][j] * D[c][j];
    }
    if (tid < m) {
      const int i = k0 + NB + tid;
      float a[NB];
      #pragma unroll
      for (int j = 0; j < NB; ++j) a[j] = Ls[i * 121 + k0 + j];
      #pragma unroll
      for (int j = 0; j < NB; ++j) {
        float v = a[j];
        #pragma unroll
        for (int l = 0; l < j; ++l) v -= a[l] * D[j][l];
        a[j] = v * di[j];
      }
      #pragma unroll
      for (int j = 0; j < NB; ++j) Ls[i * 121 + k0 + j] = a[j];
    }
    __syncthreads();

    // phase 2: tid0 writes factored diag + ivs; all threads rank-8 update
    // the m x m trailing square (regular rect, symmetric-consistent).
    if (tid == 0) {
      #pragma unroll
      for (int i = 0; i < NB; ++i) {
        #pragma unroll
        for (int j = 0; j <= i; ++j) Ls[(k0 + i) * 121 + k0 + j] = D[i][j];
        ivs[k0 + i] = di[i];
      }
    }
    if (m > 0) {
      const int cq = tid & 31;
      const int g = tid >> 5;
      if (4 * cq < m) {
        const int j0 = k0 + NB + 4 * cq;
        float pc[4][NB];
        #pragma unroll
        for (int qq = 0; qq < 4; ++qq)
          #pragma unroll
          for (int l = 0; l < NB; ++l)
            pc[qq][l] = Ls[(j0 + qq) * 121 + k0 + l];
        for (int i = k0 + NB + g; i < KD; i += 16) {
          float pr[NB];
          #pragma unroll
          for (int l = 0; l < NB; ++l) pr[l] = Ls[i * 121 + k0 + l];
          float* row = &Ls[i * 121 + j0];
          float d0 = row[0], d1 = row[1], d2 = row[2], d3 = row[3];
          #pragma unroll
          for (int l = 0; l < NB; ++l) {
            d0 -= pr[l] * pc[0][l];
            d1 -= pr[l] * pc[1][l];
            d2 -= pr[l] * pc[2][l];
            d3 -= pr[l] * pc[3][l];
          }
          row[0] = d0; row[1] = d1; row[2] = d2; row[3] = d3;
        }
      }
    }
    __syncthreads();
  }

  // ---------------- forward solve: L y = B ----------------
  for (int kb = 0; kb < NSTEP; ++kb) {
    const int k0 = kb * NB;
    if (tid < 128) {
      float Dl[NB][NB];
      #pragma unroll
      for (int i = 1; i < NB; ++i)
        #pragma unroll
        for (int j = 0; j < i; ++j)
          Dl[i][j] = Ls[(k0 + i) * 121 + k0 + j];
      float iv[NB];
      #pragma unroll
      for (int j = 0; j < NB; ++j) iv[j] = ivs[k0 + j];
      float y[NB];
      #pragma unroll
      for (int j = 0; j < NB; ++j) y[j] = xs[(k0 + j) * 128 + tid];
      #pragma unroll
      for (int j = 0; j < NB; ++j) {
        float v = y[j];
        #pragma unroll
        for (int l = 0; l < j; ++l) v -= Dl[j][l] * y[l];
        v *= iv[j];
        y[j] = v;
        xs[(k0 + j) * 128 + tid] = v;
      }
    }
    __syncthreads();
    const int m = KD - k0 - NB;
    if (m > 0) {
      const int cq = tid & 31, g = tid >> 5;
      const int co = 4 * cq;
      float4 v8[NB];
      #pragma unroll
      for (int j = 0; j < NB; ++j) v8[j] = *(const float4*)&xs[(k0 + j) * 128 + co];
      for (int i = k0 + NB + g; i < KD; i += 16) {
        float lp[NB];
        #pragma unroll
        for (int j = 0; j < NB; ++j) lp[j] = Ls[i * 121 + k0 + j];
        float4* dst = (float4*)&xs[i * 128 + co];
        float4 d = *dst;
        #pragma unroll
        for (int j = 0; j < NB; ++j) {
          d.x -= lp[j] * v8[j].x; d.y -= lp[j] * v8[j].y;
          d.z -= lp[j] * v8[j].z; d.w -= lp[j] * v8[j].w;
        }
        *dst = d;
      }
    }
    __syncthreads();
  }

  // ---------------- backward solve: L^T x = y ----------------
  for (int kb = NSTEP - 1; kb >= 0; --kb) {
    const int k0 = kb * NB;
    if (tid < 128) {
      float Dl[NB][NB];
      #pragma unroll
      for (int i = 1; i < NB; ++i)
        #pragma unroll
        for (int j = 0; j < i; ++j)
          Dl[i][j] = Ls[(k0 + i) * 121 + k0 + j];
      float iv[NB];
      #pragma unroll
      for (int j = 0; j < NB; ++j) iv[j] = ivs[k0 + j];
      float y[NB];
      #pragma unroll
      for (int j = 0; j < NB; ++j) y[j] = xs[(k0 + j) * 128 + tid];
      #pragma unroll
      for (int j = NB - 1; j >= 0; --j) {
        float v = y[j];
        #pragma unroll
        for (int l = j + 1; l < NB; ++l) v -= Dl[l][j] * y[l];
        v *= iv[j];
        y[j] = v;
        xs[(k0 + j) * 128 + tid] = v;
      }
    }
    __syncthreads();
    if (k0 > 0) {
      const int cq = tid & 31, g = tid >> 5;
      const int co = 4 * cq;
      float4 v8[NB];
      #pragma unroll
      for (int j = 0; j < NB; ++j) v8[j] = *(const float4*)&xs[(k0 + j) * 128 + co];
      for (int i = g; i < k0; i += 16) {
        float lp[NB];
        #pragma unroll
        for (int j = 0; j < NB; ++j) lp[j] = Ls[(k0 + j) * 121 + i];
        float4* dst = (float4*)&xs[i * 128 + co];
        float4 d = *dst;
        #pragma unroll
        for (int j = 0; j < NB; ++j) {
          d.x -= lp[j] * v8[j].x; d.y -= lp[j] * v8[j].y;
          d.z -= lp[j] * v8[j].z; d.w -= lp[j] * v8[j].w;
        }
        *dst = d;
      }
    }
    __syncthreads();
  }

  // output: Co[t][k] = xs[k][t]  (x fully scaled)
  float* Co = out + (size_t)which * BATCH * KD * KD + (size_t)b * KD * KD;
  {
    int t = tid & 127, gg = tid >> 7;
    if (t < KD)
      for (int k = gg; k < KD; k += 4)
        Co[(size_t)t * KD + k] = xs[k * 128 + t];
  }
}

// ---------------------------------------------------------------------------
extern "C" void kernel_launch(void* const* d_in, const int* in_sizes, int n_in,
                              void* d_out, int out_size, void* d_ws, size_t ws_size,
                              hipStream_t stream) {
  (void)in_sizes; (void)n_in; (void)out_size; (void)ws_size;
  const float* feat_x = (const float*)d_in[0];
  const float* feat_y = (const float*)d_in[1];
  const float* evecs_x = (const float*)d_in[2];
  const float* evecs_y = (const float*)d_in[3];
  const float* W1 = (const float*)d_in[4];
  const float* b1 = (const float*)d_in[5];
  const float* W2 = (const float*)d_in[6];
  const float* b2 = (const float*)d_in[7];
  const float* gamma = (const float*)d_in[8];
  const float* beta = (const float*)d_in[9];
  float* out = (float*)d_out;

  char* p = (char*)d_ws;
  auto carve = [&](size_t bytes) { char* r = p; p += (bytes + 255) & ~(size_t)255; return r; };
  short* W1t = (short*)carve(7ull * DP * DP * 2);
  short* W2t = (short*)carve(7ull * DP * DP * 2);
  short* X  = (short*)carve((size_t)RROWS * DP * 2);
  short* T1 = (short*)carve((size_t)RROWS * DP * 2);
  short* T2 = (short*)carve((size_t)RROWS * DP * 2);
  short* Eb = (short*)carve((size_t)BATCH * NVERT * KDP * 2);
  float* stats = (float*)carve(4ull * DP * 4);
  float* Fh = (float*)carve(2ull * BATCH * KDP * DP * 4);
  float* gram = (float*)carve((size_t)BATCH * 3 * KD * KD * 4);
  float* statsA = stats;
  float* statsB = stats + 2 * DP;

  hipMemsetAsync(Fh, 0, 2ull * BATCH * KDP * DP * 4, stream);
  prep_w<<<dim3((7 * DP * DP) / 256, 2), 256, 0, stream>>>(W1, W2, W1t, W2t);

  const int MT = (RROWS + 127) / 128;  // 431
  const int ET = (NVERT * 16 + 255) / 256;  // 431
  for (int f = 0; f < 2; ++f) {
    const float* feat = f ? feat_y : feat_x;
    const float* ev = f ? evecs_y : evecs_x;
    float* fxo = out + 2 * BATCH * KD * KD + (size_t)f * RROWS * DIN;
    cast_in<<<MT, 192, 0, stream>>>(feat, X, statsA);
    cast_e<<<dim3(ET, BATCH), 256, 0, stream>>>(ev, Eb);
    for (int blk = 0; blk < NBLK; ++blk) {
      // gemm1: plain A=X, accumulate statsA; zero statsB (idle this kernel)
      gemm_bn<<<dim3(MT, 3), 256, 0, stream>>>(X, W1t + (size_t)blk * DP * DP, T1, b1 + blk * DIN,
                                               statsA, statsB);
      // gemm2: fused elt_bn (affine+relu from statsA) on A=T1, accumulate statsB
      gemm_bn_f<<<dim3(MT, 3), 256, 0, stream>>>(T1, W2t + (size_t)blk * DP * DP, T2, b2 + blk * DIN,
                                                 statsB, statsA, gamma + blk * DIN, beta + blk * DIN);
      // residual: X = relu(bn(T2) + X); zero statsA for next block's gemm1
      elt_res<<<MT, 192, 0, stream>>>(T2, X, statsB, gamma + blk * DIN, beta + blk * DIN, statsA,
                                      (blk == NBLK - 1) ? fxo : (float*)nullptr);
    }
    fh_mfma<<<dim3(FH_S, 3, BATCH), 256, 0, stream>>>(Eb, X, Fh + (size_t)f * BATCH * KDP * DP);
  }
  gram_kern<<<dim3(3, BATCH), 256, 0, stream>>>(Fh, gram);
  chol_solve<<<16, 512, 0, stream>>>(gram, out);
}

// Round 4
// 2705.297 us; speedup vs baseline: 1.5107x; 1.2007x over previous
//
#include <hip/hip_runtime.h>
#include <hip/hip_bf16.h>
#include <stdint.h>
#include <stddef.h>

#define RROWS 55120   // 8*6890 rows
#define DIN   352
#define DP    384     // padded channel dim
#define NBLK  7
#define KD    120     // eigenbasis size
#define KDP   128     // padded
#define BATCH 8
#define NVERT 6890
#define BN_EPS 1e-3f
#define FH_S  16      // split-K chunks for Fh GEMM
#define NB    8       // chol/solve panel width
#define NSTEP (KD / NB)
#define GEMM_WG 1293  // 431 m-tiles x 3 n-tiles

typedef __attribute__((ext_vector_type(8))) short short8;
typedef __attribute__((ext_vector_type(4))) float floatx4;

__device__ __forceinline__ short f2bf(float f) {
  union { float f; uint32_t u; } v; v.f = f;
  uint32_t r = (v.u + 0x7fffu + ((v.u >> 16) & 1u)) >> 16;  // RNE
  return (short)r;
}
__device__ __forceinline__ float bf2f(short s) {
  union { uint32_t u; float f; } v; v.u = ((uint32_t)(uint16_t)s) << 16;
  return v.f;
}

// XCD-bijective swizzle (m204): hardware round-robins consecutive blockIdx
// across the 8 XCDs; remap so each XCD executes a CONTIGUOUS chunk of the
// logical work order. Logical order is trio-major (m*3+n), so the 3 n-tiles
// sharing an A-panel are adjacent in time on the same XCD -> A L2-hits.
__device__ __forceinline__ int xcd_swz(int bid, int nwg) {
  const int xcd = bid & 7;
  const int idx = bid >> 3;
  const int q = nwg >> 3, r = nwg & 7;
  const int start = (xcd < r) ? xcd * (q + 1) : r * (q + 1) + (xcd - r) * q;
  return start + idx;
}

// ---------------------------------------------------------------------------
// Weight prep: Wt[blk][n][k] = bf16(W[blk][k][n]), zero-padded 352->384
// ---------------------------------------------------------------------------
__global__ __launch_bounds__(256) void prep_w(const float* __restrict__ W1, const float* __restrict__ W2,
                                              short* __restrict__ W1t, short* __restrict__ W2t) {
  int e = blockIdx.x * 256 + threadIdx.x;
  const float* W = blockIdx.y ? W2 : W1;
  short* Wt = blockIdx.y ? W2t : W1t;
  int blk = e / (DP * DP);
  int rem = e - blk * DP * DP;
  int n = rem / DP;
  int k = rem - n * DP;
  float v = (n < DIN && k < DIN) ? W[(size_t)blk * DIN * DIN + (size_t)k * DIN + n] : 0.f;
  Wt[e] = f2bf(v);
}

// ---------------------------------------------------------------------------
// cast evecs fp32 [b][n][120] -> bf16 [b][n][128] (padded)
// ---------------------------------------------------------------------------
__global__ __launch_bounds__(256) void cast_e(const float* __restrict__ E, short* __restrict__ Eb) {
  int idx = blockIdx.x * 256 + threadIdx.x;
  int u8 = idx & 15;
  int n = idx >> 4;
  if (n >= NVERT) return;
  int b = blockIdx.y;
  short8 o;
  if (u8 < 15) {
    const float* src = E + ((size_t)b * NVERT + n) * KD + u8 * 8;
    #pragma unroll
    for (int j = 0; j < 8; ++j) o[j] = f2bf(src[j]);
  } else {
    #pragma unroll
    for (int j = 0; j < 8; ++j) o[j] = 0;
  }
  *(short8*)(Eb + ((size_t)b * NVERT + n) * KDP + u8 * 8) = o;
}

// ---------------------------------------------------------------------------
// cast input fp32 -> bf16, pad channels to 384; block 0 zeroes statsA
// ---------------------------------------------------------------------------
__global__ __launch_bounds__(192) void cast_in(const float* __restrict__ F, short* __restrict__ X,
                                               float* __restrict__ zbuf) {
  int tid = threadIdx.x;
  if (blockIdx.x == 0)
    for (int z = tid; z < 2 * DP; z += 192) zbuf[z] = 0.f;
  int cg = tid % 48, rl = tid / 48;
  int c0 = cg * 8;
  int row0 = blockIdx.x * 128;
  for (int rr = rl; rr < 128; rr += 4) {
    int row = row0 + rr;
    if (row >= RROWS) break;
    short8 o;
    if (c0 < DIN) {
      const float* src = F + (size_t)row * DIN + c0;
      #pragma unroll
      for (int j = 0; j < 8; ++j) o[j] = f2bf(src[j]);
    } else {
      #pragma unroll
      for (int j = 0; j < 8; ++j) o[j] = 0;
    }
    *(short8*)(X + (size_t)row * DP + c0) = o;
  }
}

// ---------------------------------------------------------------------------
// GEMM: Y[m][n] = A[m][:] @ Wt[n][:] + bias[n]   (bf16 in, bf16 out, fp32 acc)
// fused per-column sum / sumsq atomically into stats; block 0 zeroes zb.
// 1-D grid (1293) + XCD swizzle: trio of n-tiles per A-panel co-located.
// ---------------------------------------------------------------------------
__global__ __launch_bounds__(256) void gemm_bn(
    const short* __restrict__ A, const short* __restrict__ Bt,
    short* __restrict__ Y, const float* __restrict__ bias,
    float* __restrict__ stats, float* __restrict__ zb) {
  __shared__ short As[128 * 64];
  __shared__ short Bs[128 * 64];
  const int tid = threadIdx.x;
  const int lane = tid & 63;
  const int w = tid >> 6;
  const int wgid = xcd_swz(blockIdx.x, GEMM_WG);
  const int m0 = (wgid / 3) * 128;
  const int n0 = (wgid % 3) * 128;

  if (blockIdx.x == 0)
    for (int z = tid; z < 2 * DP; z += 256) zb[z] = 0.f;

  const int rsub = lane >> 3;
  const int gsw = (lane & 7) ^ rsub;

  const short* aSrc[4]; const short* bSrc[4];
  short* aDst[4]; short* bDst[4];
  #pragma unroll
  for (int t = 0; t < 4; ++t) {
    int r = 32 * w + 8 * t + rsub;
    int gm = m0 + r; if (gm >= RROWS) gm = RROWS - 1;
    aSrc[t] = A + (size_t)gm * DP + gsw * 8;
    bSrc[t] = Bt + (size_t)(n0 + r) * DP + gsw * 8;
    aDst[t] = &As[(32 * w + 8 * t) * 64];
    bDst[t] = &Bs[(32 * w + 8 * t) * 64];
  }

  floatx4 acc[4][4];
  #pragma unroll
  for (int i = 0; i < 4; ++i)
    #pragma unroll
    for (int j = 0; j < 4; ++j)
      acc[i][j] = (floatx4){0.f, 0.f, 0.f, 0.f};

  const int l15 = lane & 15;
  const int q = lane >> 4;
  const int wm = 64 * (w >> 1);
  const int wn = 64 * (w & 1);

  for (int kt = 0; kt < DP / 64; ++kt) {
    __syncthreads();
    #pragma unroll
    for (int t = 0; t < 4; ++t) {
      __builtin_amdgcn_global_load_lds((const __attribute__((address_space(1))) void*)(aSrc[t] + kt * 64),
                                       (__attribute__((address_space(3))) void*)aDst[t], 16, 0, 0);
      __builtin_amdgcn_global_load_lds((const __attribute__((address_space(1))) void*)(bSrc[t] + kt * 64),
                                       (__attribute__((address_space(3))) void*)bDst[t], 16, 0, 0);
    }
    __syncthreads();
    #pragma unroll
    for (int ks = 0; ks < 2; ++ks) {
      const int pos8 = ((((ks << 2) | q)) ^ (l15 & 7)) * 8;
      short8 af[4], bfv[4];
      #pragma unroll
      for (int mt = 0; mt < 4; ++mt)
        af[mt] = *(const short8*)&As[(wm + 16 * mt + l15) * 64 + pos8];
      #pragma unroll
      for (int nt = 0; nt < 4; ++nt)
        bfv[nt] = *(const short8*)&Bs[(wn + 16 * nt + l15) * 64 + pos8];
      #pragma unroll
      for (int mt = 0; mt < 4; ++mt)
        #pragma unroll
        for (int nt = 0; nt < 4; ++nt)
          acc[mt][nt] = __builtin_amdgcn_mfma_f32_16x16x32_bf16(af[mt], bfv[nt], acc[mt][nt], 0, 0, 0);
    }
  }

  const int mwb = m0 + wm;
  const int nwb = n0 + wn;
  #pragma unroll
  for (int nt = 0; nt < 4; ++nt) {
    const int n = nwb + 16 * nt + l15;
    const float bv = (n < DIN) ? bias[n] : 0.f;
    float s1 = 0.f, s2 = 0.f;
    #pragma unroll
    for (int mt = 0; mt < 4; ++mt) {
      const int mb = mwb + 16 * mt + 4 * q;
      #pragma unroll
      for (int v = 0; v < 4; ++v) {
        const int m = mb + v;
        if (m < RROWS) {
          float val = acc[mt][nt][v] + bv;
          Y[(size_t)m * DP + n] = f2bf(val);
          s1 += val;
          s2 += val * val;
        }
      }
    }
    s1 += __shfl_xor(s1, 16);
    s2 += __shfl_xor(s2, 16);
    s1 += __shfl_xor(s1, 32);
    s2 += __shfl_xor(s2, 32);
    if (q == 0) {
      atomicAdd(&stats[n], s1);
      atomicAdd(&stats[DP + n], s2);
    }
  }
}

// ---------------------------------------------------------------------------
// Fused elt_bn + GEMM: A-operand = relu(av*bf2f(Ain)+bb) computed in-flight
// during reg-staged A load (affine table in LDS from pstats). B via gload_lds.
// ---------------------------------------------------------------------------
__global__ __launch_bounds__(256) void gemm_bn_f(
    const short* __restrict__ A, const short* __restrict__ Bt,
    short* __restrict__ Y, const float* __restrict__ bias,
    float* __restrict__ stats, const float* __restrict__ pstats,
    const float* __restrict__ gamma, const float* __restrict__ beta) {
  __shared__ short As[128 * 64];
  __shared__ short Bs[128 * 64];
  __shared__ float avs[DP];
  __shared__ float bbs[DP];
  const int tid = threadIdx.x;
  const int lane = tid & 63;
  const int w = tid >> 6;
  const int wgid = xcd_swz(blockIdx.x, GEMM_WG);
  const int m0 = (wgid / 3) * 128;
  const int n0 = (wgid % 3) * 128;

  // affine table from producer stats
  for (int c = tid; c < DP; c += 256) {
    float mean = pstats[c] * (1.f / RROWS);
    float var = pstats[DP + c] * (1.f / RROWS) - mean * mean;
    float istd = rsqrtf(var + BN_EPS);
    float g = (c < DIN) ? gamma[c] : 0.f;
    float b = (c < DIN) ? beta[c] : 0.f;
    avs[c] = g * istd;
    bbs[c] = b - g * istd * mean;
  }

  const int rsub = lane >> 3;
  const int gsw = (lane & 7) ^ rsub;

  const short* aSrc[4]; const short* bSrc[4];
  short* bDst[4];
  #pragma unroll
  for (int t = 0; t < 4; ++t) {
    int r = 32 * w + 8 * t + rsub;
    int gm = m0 + r; if (gm >= RROWS) gm = RROWS - 1;
    aSrc[t] = A + (size_t)gm * DP + gsw * 8;
    bSrc[t] = Bt + (size_t)(n0 + r) * DP + gsw * 8;
    bDst[t] = &Bs[(32 * w + 8 * t) * 64];
  }

  floatx4 acc[4][4];
  #pragma unroll
  for (int i = 0; i < 4; ++i)
    #pragma unroll
    for (int j = 0; j < 4; ++j)
      acc[i][j] = (floatx4){0.f, 0.f, 0.f, 0.f};

  const int l15 = lane & 15;
  const int q = lane >> 4;
  const int wm = 64 * (w >> 1);
  const int wn = 64 * (w & 1);

  for (int kt = 0; kt < DP / 64; ++kt) {
    __syncthreads();   // also covers the affine-table build on first pass
    #pragma unroll
    for (int t = 0; t < 4; ++t)
      __builtin_amdgcn_global_load_lds((const __attribute__((address_space(1))) void*)(bSrc[t] + kt * 64),
                                       (__attribute__((address_space(3))) void*)bDst[t], 16, 0, 0);
    // A tile: reg-staged, affine+relu applied, written in identical layout
    {
      const int ch0 = kt * 64 + gsw * 8;
      float4 a0 = *(const float4*)&avs[ch0];
      float4 a1 = *(const float4*)&avs[ch0 + 4];
      float4 c0 = *(const float4*)&bbs[ch0];
      float4 c1 = *(const float4*)&bbs[ch0 + 4];
      float av8[8] = {a0.x, a0.y, a0.z, a0.w, a1.x, a1.y, a1.z, a1.w};
      float bb8[8] = {c0.x, c0.y, c0.z, c0.w, c1.x, c1.y, c1.z, c1.w};
      short8 ya[4];
      #pragma unroll
      for (int t = 0; t < 4; ++t) ya[t] = *(const short8*)(aSrc[t] + kt * 64);
      #pragma unroll
      for (int t = 0; t < 4; ++t) {
        short8 h;
        #pragma unroll
        for (int j = 0; j < 8; ++j) {
          float v = av8[j] * bf2f(ya[t][j]) + bb8[j];
          h[j] = f2bf(fmaxf(v, 0.f));
        }
        *(short8*)&As[(32 * w + 8 * t + rsub) * 64 + (lane & 7) * 8] = h;
      }
    }
    __syncthreads();
    #pragma unroll
    for (int ks = 0; ks < 2; ++ks) {
      const int pos8 = ((((ks << 2) | q)) ^ (l15 & 7)) * 8;
      short8 af[4], bfv[4];
      #pragma unroll
      for (int mt = 0; mt < 4; ++mt)
        af[mt] = *(const short8*)&As[(wm + 16 * mt + l15) * 64 + pos8];
      #pragma unroll
      for (int nt = 0; nt < 4; ++nt)
        bfv[nt] = *(const short8*)&Bs[(wn + 16 * nt + l15) * 64 + pos8];
      #pragma unroll
      for (int mt = 0; mt < 4; ++mt)
        #pragma unroll
        for (int nt = 0; nt < 4; ++nt)
          acc[mt][nt] = __builtin_amdgcn_mfma_f32_16x16x32_bf16(af[mt], bfv[nt], acc[mt][nt], 0, 0, 0);
    }
  }

  const int mwb = m0 + wm;
  const int nwb = n0 + wn;
  #pragma unroll
  for (int nt = 0; nt < 4; ++nt) {
    const int n = nwb + 16 * nt + l15;
    const float bv = (n < DIN) ? bias[n] : 0.f;
    float s1 = 0.f, s2 = 0.f;
    #pragma unroll
    for (int mt = 0; mt < 4; ++mt) {
      const int mb = mwb + 16 * mt + 4 * q;
      #pragma unroll
      for (int v = 0; v < 4; ++v) {
        const int m = mb + v;
        if (m < RROWS) {
          float val = acc[mt][nt][v] + bv;
          Y[(size_t)m * DP + n] = f2bf(val);
          s1 += val;
          s2 += val * val;
        }
      }
    }
    s1 += __shfl_xor(s1, 16);
    s2 += __shfl_xor(s2, 16);
    s1 += __shfl_xor(s1, 32);
    s2 += __shfl_xor(s2, 32);
    if (q == 0) {
      atomicAdd(&stats[n], s1);
      atomicAdd(&stats[DP + n], s2);
    }
  }
}

// ---------------------------------------------------------------------------
// ELT2: X = relu(bn(Y) + X); optional fp32 write of result into d_out
// ---------------------------------------------------------------------------
__global__ __launch_bounds__(192) void elt_res(
    const short* __restrict__ Yin, short* __restrict__ X,
    const float* __restrict__ stats, const float* __restrict__ gamma, const float* __restrict__ beta,
    float* __restrict__ zbuf, float* __restrict__ fout) {
  int tid = threadIdx.x;
  if (blockIdx.x == 0)
    for (int z = tid; z < 2 * DP; z += 192) zbuf[z] = 0.f;
  int cg = tid % 48, rl = tid / 48;
  int c0 = cg * 8;
  float av[8], bb[8];
  #pragma unroll
  for (int j = 0; j < 8; ++j) {
    int c = c0 + j;
    float mean = stats[c] * (1.f / RROWS);
    float var = stats[DP + c] * (1.f / RROWS) - mean * mean;
    float istd = rsqrtf(var + BN_EPS);
    float g = (c < DIN) ? gamma[c] : 0.f;
    float b = (c < DIN) ? beta[c] : 0.f;
    av[j] = g * istd;
    bb[j] = b - g * istd * mean;
  }
  int row0 = blockIdx.x * 128;
  for (int rr = rl; rr < 128; rr += 4) {
    int row = row0 + rr;
    if (row >= RROWS) break;
    size_t off = (size_t)row * DP + c0;
    short8 y = *(const short8*)(Yin + off);
    short8 x = *(const short8*)(X + off);
    short8 h;
    float vr[8];
    #pragma unroll
    for (int j = 0; j < 8; ++j) {
      float v = av[j] * bf2f(y[j]) + bb[j] + bf2f(x[j]);
      v = fmaxf(v, 0.f);
      vr[j] = v;
      h[j] = f2bf(v);
    }
    *(short8*)(X + off) = h;
    if (fout != nullptr && c0 < DIN) {
      float4 o0 = make_float4(vr[0], vr[1], vr[2], vr[3]);
      float4 o1 = make_float4(vr[4], vr[5], vr[6], vr[7]);
      *(float4*)(fout + (size_t)row * DIN + c0) = o0;
      *(float4*)(fout + (size_t)row * DIN + c0 + 4) = o1;
    }
  }
}

// ---------------------------------------------------------------------------
// Fh GEMM (bf16 MFMA, split-K, LDS-transpose staging):
//   Fh[u][v] += sum_n E[n][u] * X[n][v]   per batch b
// ---------------------------------------------------------------------------
__global__ __launch_bounds__(256) void fh_mfma(const short* __restrict__ Eb, const short* __restrict__ X,
                                               float* __restrict__ Fh) {
  __shared__ short Es[128 * 72];
  __shared__ short Xs[128 * 72];
  const int tid = threadIdx.x;
  const int lane = tid & 63;
  const int w = tid >> 6;
  const int b = blockIdx.z;
  const int v0 = blockIdx.y * 128;
  const int chunk = (NVERT + FH_S - 1) / FH_S;  // 431
  const int kbase = blockIdx.x * chunk;
  const int nend = min(kbase + chunk, NVERT);
  const int np = tid & 31;
  const int ug = tid >> 5;

  const short* Ebase = Eb + (size_t)b * NVERT * KDP;
  const short* Xbase = X + (size_t)b * NVERT * DP + v0;

  floatx4 acc[4][4];
  #pragma unroll
  for (int i = 0; i < 4; ++i)
    #pragma unroll
    for (int j = 0; j < 4; ++j)
      acc[i][j] = (floatx4){0.f, 0.f, 0.f, 0.f};

  const int l15 = lane & 15;
  const int q = lane >> 4;
  const int wm = 64 * (w >> 1);
  const int wn = 64 * (w & 1);

  const int ntiles = (nend - kbase + 63) >> 6;
  for (int kt = 0; kt < ntiles; ++kt) {
    const int nb = kbase + kt * 64;
    const int n0 = nb + 2 * np;
    const bool ok0 = (n0 < nend);
    const bool ok1 = (n0 + 1 < nend);
    __syncthreads();
    #pragma unroll
    for (int i = 0; i < 2; ++i) {
      const int u0 = ug * 16 + 8 * i;
      short8 z;
      #pragma unroll
      for (int j = 0; j < 8; ++j) z[j] = 0;
      short8 e0 = z, e1 = z, x0 = z, x1 = z;
      if (ok0) {
        e0 = *(const short8*)(Ebase + (size_t)n0 * KDP + u0);
        x0 = *(const short8*)(Xbase + (size_t)n0 * DP + u0);
      }
      if (ok1) {
        e1 = *(const short8*)(Ebase + (size_t)(n0 + 1) * KDP + u0);
        x1 = *(const short8*)(Xbase + (size_t)(n0 + 1) * DP + u0);
      }
      #pragma unroll
      for (int j = 0; j < 8; ++j) {
        uint32_t ep = (uint32_t)(uint16_t)e0[j] | ((uint32_t)(uint16_t)e1[j] << 16);
        uint32_t xp = (uint32_t)(uint16_t)x0[j] | ((uint32_t)(uint16_t)x1[j] << 16);
        *(uint32_t*)&Es[(u0 + j) * 72 + 2 * np] = ep;
        *(uint32_t*)&Xs[(u0 + j) * 72 + 2 * np] = xp;
      }
    }
    __syncthreads();
    #pragma unroll
    for (int ks = 0; ks < 2; ++ks) {
      const int ko = ks * 32 + q * 8;
      short8 af[4], bfv[4];
      #pragma unroll
      for (int mt = 0; mt < 4; ++mt)
        af[mt] = *(const short8*)&Es[(wm + 16 * mt + l15) * 72 + ko];
      #pragma unroll
      for (int nt = 0; nt < 4; ++nt)
        bfv[nt] = *(const short8*)&Xs[(wn + 16 * nt + l15) * 72 + ko];
      #pragma unroll
      for (int mt = 0; mt < 4; ++mt)
        #pragma unroll
        for (int nt = 0; nt < 4; ++nt)
          acc[mt][nt] = __builtin_amdgcn_mfma_f32_16x16x32_bf16(af[mt], bfv[nt], acc[mt][nt], 0, 0, 0);
    }
  }

  float* Fo = Fh + (size_t)b * (KDP * DP);
  #pragma unroll
  for (int nt = 0; nt < 4; ++nt) {
    const int v = wn + 16 * nt + l15;
    #pragma unroll
    for (int mt = 0; mt < 4; ++mt) {
      const int ub = wm + 16 * mt + 4 * q;
      #pragma unroll
      for (int vi = 0; vi < 4; ++vi) {
        const int u = ub + vi;
        if (u < KD)
          atomicAdd(&Fo[(size_t)u * DP + v0 + v], acc[mt][nt][vi]);
      }
    }
  }
}

// ---------------------------------------------------------------------------
// Gram: mat0=FtF, mat1=FtG, mat2=GtG; split-D over 12 chunks of 32 (grid.z),
// atomicAdd into zeroed G. 24 -> 288 blocks (was 1% occupancy, LDS-latency
// bound at 122us with only 24 CUs active).
// ---------------------------------------------------------------------------
__global__ __launch_bounds__(256) void gram_kern(const float* __restrict__ Fh, float* __restrict__ G) {
  __shared__ float As[128 * 33];
  __shared__ float Bs[32 * 132];
  int mat = blockIdx.x, b = blockIdx.y;
  const float* Pa = Fh + (size_t)((mat == 2 ? BATCH : 0) + b) * KDP * DP;
  const float* Pb = Fh + (size_t)((mat == 0 ? 0 : BATCH) + b) * KDP * DP;
  int tid = threadIdx.x;
  int ty = tid >> 4, tx = tid & 15;
  float accv[8][8];
  #pragma unroll
  for (int i = 0; i < 8; ++i)
    #pragma unroll
    for (int j = 0; j < 8; ++j) accv[i][j] = 0.f;
  const int d0 = blockIdx.z * 32;
  #pragma unroll
  for (int j = 0; j < 16; ++j) {
    int e = tid + 256 * j;
    int r = e >> 5, c = e & 31;
    float va = (r < KD) ? Pa[(size_t)r * DP + d0 + c] : 0.f;
    float vb = (r < KD) ? Pb[(size_t)r * DP + d0 + c] : 0.f;
    As[r * 33 + c] = va;
    Bs[c * 132 + r] = vb;
  }
  __syncthreads();
  for (int dd = 0; dd < 32; ++dd) {
    float a[8], bv[8];
    #pragma unroll
    for (int i = 0; i < 8; ++i) a[i] = As[(8 * ty + i) * 33 + dd];
    float4 b0 = *(const float4*)&Bs[dd * 132 + 8 * tx];
    float4 b1 = *(const float4*)&Bs[dd * 132 + 8 * tx + 4];
    bv[0] = b0.x; bv[1] = b0.y; bv[2] = b0.z; bv[3] = b0.w;
    bv[4] = b1.x; bv[5] = b1.y; bv[6] = b1.z; bv[7] = b1.w;
    #pragma unroll
    for (int i = 0; i < 8; ++i)
      #pragma unroll
      for (int j = 0; j < 8; ++j)
        accv[i][j] += a[i] * bv[j];
  }
  float* Go = G + (size_t)(b * 3 + mat) * KD * KD;
  #pragma unroll
  for (int i = 0; i < 8; ++i) {
    int k = 8 * ty + i;
    if (k < KD)
      #pragma unroll
      for (int j = 0; j < 8; ++j) {
        int l = 8 * tx + j;
        if (l < KD) atomicAdd(&Go[k * KD + l], accv[i][j]);
      }
  }
}

// ---------------------------------------------------------------------------
// Fused BLOCKED Cholesky + triangular solves (NB=8 panels, 15 steps each).
// ---------------------------------------------------------------------------
__global__ __launch_bounds__(512) void chol_solve(const float* __restrict__ G, float* __restrict__ out) {
  __shared__ float Ls[KD * 121];
  __shared__ float xs[KD * 128];
  __shared__ float ivs[KD];
  const int sys = blockIdx.x;
  const int b = sys >> 1;
  const int which = sys & 1;
  const int mat = which ? 2 : 0;
  const float* Gm = G + (size_t)(b * 3 + mat) * KD * KD;   // FtF or GtG
  const float* Bm = G + (size_t)(b * 3 + 1) * KD * KD;     // FtG
  const int tid = threadIdx.x;

  for (int e = tid; e < KD * KD; e += 512) {
    int r = e / KD, c = e - r * KD;
    Ls[r * 121 + c] = Gm[e];
  }
  {
    int t = tid & 127, g4 = tid >> 7;
    for (int k = g4; k < KD; k += 4)
      xs[k * 128 + t] = (t < KD) ? (which == 0 ? Bm[k * KD + t] : Bm[t * KD + k]) : 0.f;
  }
  __syncthreads();

  // ---------------- blocked Cholesky ----------------
  for (int kb = 0; kb < NSTEP; ++kb) {
    const int k0 = kb * NB;
    const int m = KD - k0 - NB;   // panel / trailing rows

    float D[NB][NB];
    #pragma unroll
    for (int i = 0; i < NB; ++i)
      #pragma unroll
      for (int j = 0; j <= i; ++j)
        D[i][j] = Ls[(k0 + i) * 121 + k0 + j];
    float di[NB];
    #pragma unroll
    for (int j = 0; j < NB; ++j) {
      float s = sqrtf(D[j][j]);
      float inv = 1.f / s;
      D[j][j] = s; di[j] = inv;
      #pragma unroll
      for (int i = j + 1; i < NB; ++i) D[i][j] *= inv;
      #pragma unroll
      for (int i = j + 1; i < NB; ++i)
        #pragma unroll
        for (int c = j + 1; c <= i; ++c)
          D[i][c] -= D[i][j] * D[c][j];
    }
    if (tid < m) {
      const int i = k0 + NB + tid;
      float a[NB];
      #pragma unroll
      for (int j = 0; j < NB; ++j) a[j] = Ls[i * 121 + k0 + j];
      #pragma unroll
      for (int j = 0; j < NB; ++j) {
        float v = a[j];
        #pragma unroll
        for (int l = 0; l < j; ++l) v -= a[l] * D[j][l];
        a[j] = v * di[j];
      }
      #pragma unroll
      for (int j = 0; j < NB; ++j) Ls[i * 121 + k0 + j] = a[j];
    }
    __syncthreads();

    if (tid == 0) {
      #pragma unroll
      for (int i = 0; i < NB; ++i) {
        #pragma unroll
        for (int j = 0; j <= i; ++j) Ls[(k0 + i) * 121 + k0 + j] = D[i][j];
        ivs[k0 + i] = di[i];
      }
    }
    if (m > 0) {
      const int cq = tid & 31;
      const int g = tid >> 5;
      if (4 * cq < m) {
        const int j0 = k0 + NB + 4 * cq;
        float pc[4][NB];
        #pragma unroll
        for (int qq = 0; qq < 4; ++qq)
          #pragma unroll
          for (int l = 0; l < NB; ++l)
            pc[qq][l] = Ls[(j0 + qq) * 121 + k0 + l];
        for (int i = k0 + NB + g; i < KD; i += 16) {
          float pr[NB];
          #pragma unroll
          for (int l = 0; l < NB; ++l) pr[l] = Ls[i * 121 + k0 + l];
          float* row = &Ls[i * 121 + j0];
          float d0 = row[0], d1 = row[1], d2 = row[2], d3 = row[3];
          #pragma unroll
          for (int l = 0; l < NB; ++l) {
            d0 -= pr[l] * pc[0][l];
            d1 -= pr[l] * pc[1][l];
            d2 -= pr[l] * pc[2][l];
            d3 -= pr[l] * pc[3][l];
          }
          row[0] = d0; row[1] = d1; row[2] = d2; row[3] = d3;
        }
      }
    }
    __syncthreads();
  }

  // ---------------- forward solve: L y = B ----------------
  for (int kb = 0; kb < NSTEP; ++kb) {
    const int k0 = kb * NB;
    if (tid < 128) {
      float Dl[NB][NB];
      #pragma unroll
      for (int i = 1; i < NB; ++i)
        #pragma unroll
        for (int j = 0; j < i; ++j)
          Dl[i][j] = Ls[(k0 + i) * 121 + k0 + j];
      float iv[NB];
      #pragma unroll
      for (int j = 0; j < NB; ++j) iv[j] = ivs[k0 + j];
      float y[NB];
      #pragma unroll
      for (int j = 0; j < NB; ++j) y[j] = xs[(k0 + j) * 128 + tid];
      #pragma unroll
      for (int j = 0; j < NB; ++j) {
        float v = y[j];
        #pragma unroll
        for (int l = 0; l < j; ++l) v -= Dl[j][l] * y[l];
        v *= iv[j];
        y[j] = v;
        xs[(k0 + j) * 128 + tid] = v;
      }
    }
    __syncthreads();
    const int m = KD - k0 - NB;
    if (m > 0) {
      const int cq = tid & 31, g = tid >> 5;
      const int co = 4 * cq;
      float4 v8[NB];
      #pragma unroll
      for (int j = 0; j < NB; ++j) v8[j] = *(const float4*)&xs[(k0 + j) * 128 + co];
      for (int i = k0 + NB + g; i < KD; i += 16) {
        float lp[NB];
        #pragma unroll
        for (int j = 0; j < NB; ++j) lp[j] = Ls[i * 121 + k0 + j];
        float4* dst = (float4*)&xs[i * 128 + co];
        float4 d = *dst;
        #pragma unroll
        for (int j = 0; j < NB; ++j) {
          d.x -= lp[j] * v8[j].x; d.y -= lp[j] * v8[j].y;
          d.z -= lp[j] * v8[j].z; d.w -= lp[j] * v8[j].w;
        }
        *dst = d;
      }
    }
    __syncthreads();
  }

  // ---------------- backward solve: L^T x = y ----------------
  for (int kb = NSTEP - 1; kb >= 0; --kb) {
    const int k0 = kb * NB;
    if (tid < 128) {
      float Dl[NB][NB];
      #pragma unroll
      for (int i = 1; i < NB; ++i)
        #pragma unroll
        for (int j = 0; j < i; ++j)
          Dl[i][j] = Ls[(k0 + i) * 121 + k0 + j];
      float iv[NB];
      #pragma unroll
      for (int j = 0; j < NB; ++j) iv[j] = ivs[k0 + j];
      float y[NB];
      #pragma unroll
      for (int j = 0; j < NB; ++j) y[j] = xs[(k0 + j) * 128 + tid];
      #pragma unroll
      for (int j = NB - 1; j >= 0; --j) {
        float v = y[j];
        #pragma unroll
        for (int l = j + 1; l < NB; ++l) v -= Dl[l][j] * y[l];
        v *= iv[j];
        y[j] = v;
        xs[(k0 + j) * 128 + tid] = v;
      }
    }
    __syncthreads();
    if (k0 > 0) {
      const int cq = tid & 31, g = tid >> 5;
      const int co = 4 * cq;
      float4 v8[NB];
      #pragma unroll
      for (int j = 0; j < NB; ++j) v8[j] = *(const float4*)&xs[(k0 + j) * 128 + co];
      for (int i = g; i < k0; i += 16) {
        float lp[NB];
        #pragma unroll
        for (int j = 0; j < NB; ++j) lp[j] = Ls[(k0 + j) * 121 + i];
        float4* dst = (float4*)&xs[i * 128 + co];
        float4 d = *dst;
        #pragma unroll
        for (int j = 0; j < NB; ++j) {
          d.x -= lp[j] * v8[j].x; d.y -= lp[j] * v8[j].y;
          d.z -= lp[j] * v8[j].z; d.w -= lp[j] * v8[j].w;
        }
        *dst = d;
      }
    }
    __syncthreads();
  }

  // output: Co[t][k] = xs[k][t]  (x fully scaled)
  float* Co = out + (size_t)which * BATCH * KD * KD + (size_t)b * KD * KD;
  {
    int t = tid & 127, gg = tid >> 7;
    if (t < KD)
      for (int k = gg; k < KD; k += 4)
        Co[(size_t)t * KD + k] = xs[k * 128 + t];
  }
}

// ---------------------------------------------------------------------------
extern "C" void kernel_launch(void* const* d_in, const int* in_sizes, int n_in,
                              void* d_out, int out_size, void* d_ws, size_t ws_size,
                              hipStream_t stream) {
  (void)in_sizes; (void)n_in; (void)out_size; (void)ws_size;
  const float* feat_x = (const float*)d_in[0];
  const float* feat_y = (const float*)d_in[1];
  const float* evecs_x = (const float*)d_in[2];
  const float* evecs_y = (const float*)d_in[3];
  const float* W1 = (const float*)d_in[4];
  const float* b1 = (const float*)d_in[5];
  const float* W2 = (const float*)d_in[6];
  const float* b2 = (const float*)d_in[7];
  const float* gamma = (const float*)d_in[8];
  const float* beta = (const float*)d_in[9];
  float* out = (float*)d_out;

  char* p = (char*)d_ws;
  auto carve = [&](size_t bytes) { char* r = p; p += (bytes + 255) & ~(size_t)255; return r; };
  short* W1t = (short*)carve(7ull * DP * DP * 2);
  short* W2t = (short*)carve(7ull * DP * DP * 2);
  short* X  = (short*)carve((size_t)RROWS * DP * 2);
  short* T1 = (short*)carve((size_t)RROWS * DP * 2);
  short* T2 = (short*)carve((size_t)RROWS * DP * 2);
  short* Eb = (short*)carve((size_t)BATCH * NVERT * KDP * 2);
  float* stats = (float*)carve(4ull * DP * 4);
  float* Fh = (float*)carve(2ull * BATCH * KDP * DP * 4);
  float* gram = (float*)carve((size_t)BATCH * 3 * KD * KD * 4);
  float* statsA = stats;
  float* statsB = stats + 2 * DP;

  hipMemsetAsync(Fh, 0, 2ull * BATCH * KDP * DP * 4, stream);
  hipMemsetAsync(gram, 0, (size_t)BATCH * 3 * KD * KD * 4, stream);
  prep_w<<<dim3((7 * DP * DP) / 256, 2), 256, 0, stream>>>(W1, W2, W1t, W2t);

  const int MT = (RROWS + 127) / 128;  // 431
  const int ET = (NVERT * 16 + 255) / 256;  // 431
  for (int f = 0; f < 2; ++f) {
    const float* feat = f ? feat_y : feat_x;
    const float* ev = f ? evecs_y : evecs_x;
    float* fxo = out + 2 * BATCH * KD * KD + (size_t)f * RROWS * DIN;
    cast_in<<<MT, 192, 0, stream>>>(feat, X, statsA);
    cast_e<<<dim3(ET, BATCH), 256, 0, stream>>>(ev, Eb);
    for (int blk = 0; blk < NBLK; ++blk) {
      // gemm1: plain A=X, accumulate statsA; zero statsB (idle this kernel)
      gemm_bn<<<GEMM_WG, 256, 0, stream>>>(X, W1t + (size_t)blk * DP * DP, T1, b1 + blk * DIN,
                                           statsA, statsB);
      // gemm2: fused elt_bn (affine+relu from statsA) on A=T1, accumulate statsB
      gemm_bn_f<<<GEMM_WG, 256, 0, stream>>>(T1, W2t + (size_t)blk * DP * DP, T2, b2 + blk * DIN,
                                             statsB, statsA, gamma + blk * DIN, beta + blk * DIN);
      // residual: X = relu(bn(T2) + X); zero statsA for next block's gemm1
      elt_res<<<MT, 192, 0, stream>>>(T2, X, statsB, gamma + blk * DIN, beta + blk * DIN, statsA,
                                      (blk == NBLK - 1) ? fxo : (float*)nullptr);
    }
    fh_mfma<<<dim3(FH_S, 3, BATCH), 256, 0, stream>>>(Eb, X, Fh + (size_t)f * BATCH * KDP * DP);
  }
  gram_kern<<<dim3(3, BATCH, 12), 256, 0, stream>>>(Fh, gram);
  chol_solve<<<16, 512, 0, stream>>>(gram, out);
}

// Round 5
// 2385.736 us; speedup vs baseline: 1.7130x; 1.1339x over previous
//
#include <hip/hip_runtime.h>
#include <hip/hip_bf16.h>
#include <stdint.h>
#include <stddef.h>

#define RROWS 55120   // 8*6890 rows
#define DIN   352
#define DP    384     // padded channel dim
#define NBLK  7
#define KD    120     // eigenbasis size
#define KDP   128     // padded
#define BATCH 8
#define NVERT 6890
#define BN_EPS 1e-3f
#define FH_S  16      // split-K chunks for Fh GEMM
#define NB    8       // chol/solve panel width
#define NSTEP (KD / NB)
#define GEMM_WG 1293  // 431 m-tiles x 3 n-tiles
#define GZ    12      // gram split-D chunks

typedef __attribute__((ext_vector_type(8))) short short8;
typedef __attribute__((ext_vector_type(4))) float floatx4;

__device__ __forceinline__ short f2bf(float f) {
  union { float f; uint32_t u; } v; v.f = f;
  uint32_t r = (v.u + 0x7fffu + ((v.u >> 16) & 1u)) >> 16;  // RNE
  return (short)r;
}
__device__ __forceinline__ float bf2f(short s) {
  union { uint32_t u; float f; } v; v.u = ((uint32_t)(uint16_t)s) << 16;
  return v.f;
}

// XCD-bijective swizzle (m204): each XCD executes a CONTIGUOUS chunk of the
// logical (trio-major) work order -> the 3 n-tiles sharing an A-panel are
// temporally adjacent on one XCD -> A L2-hits.
__device__ __forceinline__ int xcd_swz(int bid, int nwg) {
  const int xcd = bid & 7;
  const int idx = bid >> 3;
  const int q = nwg >> 3, r = nwg & 7;
  const int start = (xcd < r) ? xcd * (q + 1) : r * (q + 1) + (xcd - r) * q;
  return start + idx;
}

// ---------------------------------------------------------------------------
// Weight prep: Wt[blk][n][k] = bf16(W[blk][k][n]), zero-padded 352->384
// ---------------------------------------------------------------------------
__global__ __launch_bounds__(256) void prep_w(const float* __restrict__ W1, const float* __restrict__ W2,
                                              short* __restrict__ W1t, short* __restrict__ W2t) {
  int e = blockIdx.x * 256 + threadIdx.x;
  const float* W = blockIdx.y ? W2 : W1;
  short* Wt = blockIdx.y ? W2t : W1t;
  int blk = e / (DP * DP);
  int rem = e - blk * DP * DP;
  int n = rem / DP;
  int k = rem - n * DP;
  float v = (n < DIN && k < DIN) ? W[(size_t)blk * DIN * DIN + (size_t)k * DIN + n] : 0.f;
  Wt[e] = f2bf(v);
}

// ---------------------------------------------------------------------------
// cast evecs fp32 [b][n][120] -> bf16 [b][n][128] (padded)
// ---------------------------------------------------------------------------
__global__ __launch_bounds__(256) void cast_e(const float* __restrict__ E, short* __restrict__ Eb) {
  int idx = blockIdx.x * 256 + threadIdx.x;
  int u8 = idx & 15;
  int n = idx >> 4;
  if (n >= NVERT) return;
  int b = blockIdx.y;
  short8 o;
  if (u8 < 15) {
    const float* src = E + ((size_t)b * NVERT + n) * KD + u8 * 8;
    #pragma unroll
    for (int j = 0; j < 8; ++j) o[j] = f2bf(src[j]);
  } else {
    #pragma unroll
    for (int j = 0; j < 8; ++j) o[j] = 0;
  }
  *(short8*)(Eb + ((size_t)b * NVERT + n) * KDP + u8 * 8) = o;
}

// ---------------------------------------------------------------------------
// cast input fp32 -> bf16, pad channels to 384; block 0 zeroes statsA
// ---------------------------------------------------------------------------
__global__ __launch_bounds__(192) void cast_in(const float* __restrict__ F, short* __restrict__ X,
                                               float* __restrict__ zbuf) {
  int tid = threadIdx.x;
  if (blockIdx.x == 0)
    for (int z = tid; z < 2 * DP; z += 192) zbuf[z] = 0.f;
  int cg = tid % 48, rl = tid / 48;
  int c0 = cg * 8;
  int row0 = blockIdx.x * 128;
  for (int rr = rl; rr < 128; rr += 4) {
    int row = row0 + rr;
    if (row >= RROWS) break;
    short8 o;
    if (c0 < DIN) {
      const float* src = F + (size_t)row * DIN + c0;
      #pragma unroll
      for (int j = 0; j < 8; ++j) o[j] = f2bf(src[j]);
    } else {
      #pragma unroll
      for (int j = 0; j < 8; ++j) o[j] = 0;
    }
    *(short8*)(X + (size_t)row * DP + c0) = o;
  }
}

// ---------------------------------------------------------------------------
// GEMM: Y[m][n] = A[m][:] @ Wt[n][:] + bias[n]   (bf16 in, bf16 out, fp32 acc)
// Stats: LDS pre-reduction (sred) then ONE distinct-address global atomic per
// element (global fp32 atomics write through to HBM at 32B each — minimize).
// ---------------------------------------------------------------------------
__global__ __launch_bounds__(256) void gemm_bn(
    const short* __restrict__ A, const short* __restrict__ Bt,
    short* __restrict__ Y, const float* __restrict__ bias,
    float* __restrict__ stats, float* __restrict__ zb) {
  __shared__ short As[128 * 64];
  __shared__ short Bs[128 * 64];
  __shared__ float sred[256];
  const int tid = threadIdx.x;
  const int lane = tid & 63;
  const int w = tid >> 6;
  const int wgid = xcd_swz(blockIdx.x, GEMM_WG);
  const int m0 = (wgid / 3) * 128;
  const int n0 = (wgid % 3) * 128;

  if (blockIdx.x == 0)
    for (int z = tid; z < 2 * DP; z += 256) zb[z] = 0.f;
  sred[tid] = 0.f;

  const int rsub = lane >> 3;
  const int gsw = (lane & 7) ^ rsub;

  const short* aSrc[4]; const short* bSrc[4];
  short* aDst[4]; short* bDst[4];
  #pragma unroll
  for (int t = 0; t < 4; ++t) {
    int r = 32 * w + 8 * t + rsub;
    int gm = m0 + r; if (gm >= RROWS) gm = RROWS - 1;
    aSrc[t] = A + (size_t)gm * DP + gsw * 8;
    bSrc[t] = Bt + (size_t)(n0 + r) * DP + gsw * 8;
    aDst[t] = &As[(32 * w + 8 * t) * 64];
    bDst[t] = &Bs[(32 * w + 8 * t) * 64];
  }

  floatx4 acc[4][4];
  #pragma unroll
  for (int i = 0; i < 4; ++i)
    #pragma unroll
    for (int j = 0; j < 4; ++j)
      acc[i][j] = (floatx4){0.f, 0.f, 0.f, 0.f};

  const int l15 = lane & 15;
  const int q = lane >> 4;
  const int wm = 64 * (w >> 1);
  const int wn = 64 * (w & 1);

  for (int kt = 0; kt < DP / 64; ++kt) {
    __syncthreads();
    #pragma unroll
    for (int t = 0; t < 4; ++t) {
      __builtin_amdgcn_global_load_lds((const __attribute__((address_space(1))) void*)(aSrc[t] + kt * 64),
                                       (__attribute__((address_space(3))) void*)aDst[t], 16, 0, 0);
      __builtin_amdgcn_global_load_lds((const __attribute__((address_space(1))) void*)(bSrc[t] + kt * 64),
                                       (__attribute__((address_space(3))) void*)bDst[t], 16, 0, 0);
    }
    __syncthreads();
    #pragma unroll
    for (int ks = 0; ks < 2; ++ks) {
      const int pos8 = ((((ks << 2) | q)) ^ (l15 & 7)) * 8;
      short8 af[4], bfv[4];
      #pragma unroll
      for (int mt = 0; mt < 4; ++mt)
        af[mt] = *(const short8*)&As[(wm + 16 * mt + l15) * 64 + pos8];
      #pragma unroll
      for (int nt = 0; nt < 4; ++nt)
        bfv[nt] = *(const short8*)&Bs[(wn + 16 * nt + l15) * 64 + pos8];
      #pragma unroll
      for (int mt = 0; mt < 4; ++mt)
        #pragma unroll
        for (int nt = 0; nt < 4; ++nt)
          acc[mt][nt] = __builtin_amdgcn_mfma_f32_16x16x32_bf16(af[mt], bfv[nt], acc[mt][nt], 0, 0, 0);
    }
  }

  const int mwb = m0 + wm;
  #pragma unroll
  for (int nt = 0; nt < 4; ++nt) {
    const int nl = wn + 16 * nt + l15;
    const int n = n0 + nl;
    const float bv = (n < DIN) ? bias[n] : 0.f;
    float s1 = 0.f, s2 = 0.f;
    #pragma unroll
    for (int mt = 0; mt < 4; ++mt) {
      const int mb = mwb + 16 * mt + 4 * q;
      #pragma unroll
      for (int v = 0; v < 4; ++v) {
        const int m = mb + v;
        if (m < RROWS) {
          float val = acc[mt][nt][v] + bv;
          Y[(size_t)m * DP + n] = f2bf(val);
          s1 += val;
          s2 += val * val;
        }
      }
    }
    s1 += __shfl_xor(s1, 16);
    s2 += __shfl_xor(s2, 16);
    s1 += __shfl_xor(s1, 32);
    s2 += __shfl_xor(s2, 32);
    if (q == 0) {
      atomicAdd(&sred[nl], s1);
      atomicAdd(&sred[128 + nl], s2);
    }
  }
  __syncthreads();
  {
    const int half = tid >> 7, nl = tid & 127;
    atomicAdd(&stats[half * DP + n0 + nl], sred[tid]);
  }
}

// ---------------------------------------------------------------------------
// Fused elt_bn + GEMM: A-operand = relu(av*bf2f(Ain)+bb) computed in-flight
// during reg-staged A load (affine table in LDS from pstats). B via gload_lds.
// ---------------------------------------------------------------------------
__global__ __launch_bounds__(256) void gemm_bn_f(
    const short* __restrict__ A, const short* __restrict__ Bt,
    short* __restrict__ Y, const float* __restrict__ bias,
    float* __restrict__ stats, const float* __restrict__ pstats,
    const float* __restrict__ gamma, const float* __restrict__ beta) {
  __shared__ short As[128 * 64];
  __shared__ short Bs[128 * 64];
  __shared__ float avs[DP];
  __shared__ float bbs[DP];
  __shared__ float sred[256];
  const int tid = threadIdx.x;
  const int lane = tid & 63;
  const int w = tid >> 6;
  const int wgid = xcd_swz(blockIdx.x, GEMM_WG);
  const int m0 = (wgid / 3) * 128;
  const int n0 = (wgid % 3) * 128;

  // affine table from producer stats
  for (int c = tid; c < DP; c += 256) {
    float mean = pstats[c] * (1.f / RROWS);
    float var = pstats[DP + c] * (1.f / RROWS) - mean * mean;
    float istd = rsqrtf(var + BN_EPS);
    float g = (c < DIN) ? gamma[c] : 0.f;
    float b = (c < DIN) ? beta[c] : 0.f;
    avs[c] = g * istd;
    bbs[c] = b - g * istd * mean;
  }
  sred[tid] = 0.f;

  const int rsub = lane >> 3;
  const int gsw = (lane & 7) ^ rsub;

  const short* aSrc[4]; const short* bSrc[4];
  short* bDst[4];
  #pragma unroll
  for (int t = 0; t < 4; ++t) {
    int r = 32 * w + 8 * t + rsub;
    int gm = m0 + r; if (gm >= RROWS) gm = RROWS - 1;
    aSrc[t] = A + (size_t)gm * DP + gsw * 8;
    bSrc[t] = Bt + (size_t)(n0 + r) * DP + gsw * 8;
    bDst[t] = &Bs[(32 * w + 8 * t) * 64];
  }

  floatx4 acc[4][4];
  #pragma unroll
  for (int i = 0; i < 4; ++i)
    #pragma unroll
    for (int j = 0; j < 4; ++j)
      acc[i][j] = (floatx4){0.f, 0.f, 0.f, 0.f};

  const int l15 = lane & 15;
  const int q = lane >> 4;
  const int wm = 64 * (w >> 1);
  const int wn = 64 * (w & 1);

  for (int kt = 0; kt < DP / 64; ++kt) {
    __syncthreads();   // also covers the affine-table build on first pass
    #pragma unroll
    for (int t = 0; t < 4; ++t)
      __builtin_amdgcn_global_load_lds((const __attribute__((address_space(1))) void*)(bSrc[t] + kt * 64),
                                       (__attribute__((address_space(3))) void*)bDst[t], 16, 0, 0);
    // A tile: reg-staged, affine+relu applied, written in identical layout
    {
      const int ch0 = kt * 64 + gsw * 8;
      float4 a0 = *(const float4*)&avs[ch0];
      float4 a1 = *(const float4*)&avs[ch0 + 4];
      float4 c0 = *(const float4*)&bbs[ch0];
      float4 c1 = *(const float4*)&bbs[ch0 + 4];
      float av8[8] = {a0.x, a0.y, a0.z, a0.w, a1.x, a1.y, a1.z, a1.w};
      float bb8[8] = {c0.x, c0.y, c0.z, c0.w, c1.x, c1.y, c1.z, c1.w};
      short8 ya[4];
      #pragma unroll
      for (int t = 0; t < 4; ++t) ya[t] = *(const short8*)(aSrc[t] + kt * 64);
      #pragma unroll
      for (int t = 0; t < 4; ++t) {
        short8 h;
        #pragma unroll
        for (int j = 0; j < 8; ++j) {
          float v = av8[j] * bf2f(ya[t][j]) + bb8[j];
          h[j] = f2bf(fmaxf(v, 0.f));
        }
        *(short8*)&As[(32 * w + 8 * t + rsub) * 64 + (lane & 7) * 8] = h;
      }
    }
    __syncthreads();
    #pragma unroll
    for (int ks = 0; ks < 2; ++ks) {
      const int pos8 = ((((ks << 2) | q)) ^ (l15 & 7)) * 8;
      short8 af[4], bfv[4];
      #pragma unroll
      for (int mt = 0; mt < 4; ++mt)
        af[mt] = *(const short8*)&As[(wm + 16 * mt + l15) * 64 + pos8];
      #pragma unroll
      for (int nt = 0; nt < 4; ++nt)
        bfv[nt] = *(const short8*)&Bs[(wn + 16 * nt + l15) * 64 + pos8];
      #pragma unroll
      for (int mt = 0; mt < 4; ++mt)
        #pragma unroll
        for (int nt = 0; nt < 4; ++nt)
          acc[mt][nt] = __builtin_amdgcn_mfma_f32_16x16x32_bf16(af[mt], bfv[nt], acc[mt][nt], 0, 0, 0);
    }
  }

  const int mwb = m0 + wm;
  #pragma unroll
  for (int nt = 0; nt < 4; ++nt) {
    const int nl = wn + 16 * nt + l15;
    const int n = n0 + nl;
    const float bv = (n < DIN) ? bias[n] : 0.f;
    float s1 = 0.f, s2 = 0.f;
    #pragma unroll
    for (int mt = 0; mt < 4; ++mt) {
      const int mb = mwb + 16 * mt + 4 * q;
      #pragma unroll
      for (int v = 0; v < 4; ++v) {
        const int m = mb + v;
        if (m < RROWS) {
          float val = acc[mt][nt][v] + bv;
          Y[(size_t)m * DP + n] = f2bf(val);
          s1 += val;
          s2 += val * val;
        }
      }
    }
    s1 += __shfl_xor(s1, 16);
    s2 += __shfl_xor(s2, 16);
    s1 += __shfl_xor(s1, 32);
    s2 += __shfl_xor(s2, 32);
    if (q == 0) {
      atomicAdd(&sred[nl], s1);
      atomicAdd(&sred[128 + nl], s2);
    }
  }
  __syncthreads();
  {
    const int half = tid >> 7, nl = tid & 127;
    atomicAdd(&stats[half * DP + n0 + nl], sred[tid]);
  }
}

// ---------------------------------------------------------------------------
// ELT2: X = relu(bn(Y) + X); optional fp32 write of result into d_out
// ---------------------------------------------------------------------------
__global__ __launch_bounds__(192) void elt_res(
    const short* __restrict__ Yin, short* __restrict__ X,
    const float* __restrict__ stats, const float* __restrict__ gamma, const float* __restrict__ beta,
    float* __restrict__ zbuf, float* __restrict__ fout) {
  int tid = threadIdx.x;
  if (blockIdx.x == 0)
    for (int z = tid; z < 2 * DP; z += 192) zbuf[z] = 0.f;
  int cg = tid % 48, rl = tid / 48;
  int c0 = cg * 8;
  float av[8], bb[8];
  #pragma unroll
  for (int j = 0; j < 8; ++j) {
    int c = c0 + j;
    float mean = stats[c] * (1.f / RROWS);
    float var = stats[DP + c] * (1.f / RROWS) - mean * mean;
    float istd = rsqrtf(var + BN_EPS);
    float g = (c < DIN) ? gamma[c] : 0.f;
    float b = (c < DIN) ? beta[c] : 0.f;
    av[j] = g * istd;
    bb[j] = b - g * istd * mean;
  }
  int row0 = blockIdx.x * 128;
  for (int rr = rl; rr < 128; rr += 4) {
    int row = row0 + rr;
    if (row >= RROWS) break;
    size_t off = (size_t)row * DP + c0;
    short8 y = *(const short8*)(Yin + off);
    short8 x = *(const short8*)(X + off);
    short8 h;
    float vr[8];
    #pragma unroll
    for (int j = 0; j < 8; ++j) {
      float v = av[j] * bf2f(y[j]) + bb[j] + bf2f(x[j]);
      v = fmaxf(v, 0.f);
      vr[j] = v;
      h[j] = f2bf(v);
    }
    *(short8*)(X + off) = h;
    if (fout != nullptr && c0 < DIN) {
      float4 o0 = make_float4(vr[0], vr[1], vr[2], vr[3]);
      float4 o1 = make_float4(vr[4], vr[5], vr[6], vr[7]);
      *(float4*)(fout + (size_t)row * DIN + c0) = o0;
      *(float4*)(fout + (size_t)row * DIN + c0 + 4) = o1;
    }
  }
}

// ---------------------------------------------------------------------------
// Fh GEMM (bf16 MFMA, split-K, LDS-transpose staging):
//   Fp[split][b][u][v] = sum_{n in chunk} E[n][u] * X[n][v]
// Plain stores to per-split slabs (atomics write through to HBM at 32B each —
// 189MB/dispatch before; now 25MB of coalesced cached stores + fh_red).
// ---------------------------------------------------------------------------
__global__ __launch_bounds__(256) void fh_mfma(const short* __restrict__ Eb, const short* __restrict__ X,
                                               float* __restrict__ Fp) {
  __shared__ short Es[128 * 72];
  __shared__ short Xs[128 * 72];
  const int tid = threadIdx.x;
  const int lane = tid & 63;
  const int w = tid >> 6;
  const int b = blockIdx.z;
  const int v0 = blockIdx.y * 128;
  const int chunk = (NVERT + FH_S - 1) / FH_S;  // 431
  const int kbase = blockIdx.x * chunk;
  const int nend = min(kbase + chunk, NVERT);
  const int np = tid & 31;
  const int ug = tid >> 5;

  const short* Ebase = Eb + (size_t)b * NVERT * KDP;
  const short* Xbase = X + (size_t)b * NVERT * DP + v0;

  floatx4 acc[4][4];
  #pragma unroll
  for (int i = 0; i < 4; ++i)
    #pragma unroll
    for (int j = 0; j < 4; ++j)
      acc[i][j] = (floatx4){0.f, 0.f, 0.f, 0.f};

  const int l15 = lane & 15;
  const int q = lane >> 4;
  const int wm = 64 * (w >> 1);
  const int wn = 64 * (w & 1);

  const int ntiles = (nend - kbase + 63) >> 6;
  for (int kt = 0; kt < ntiles; ++kt) {
    const int nb = kbase + kt * 64;
    const int n0 = nb + 2 * np;
    const bool ok0 = (n0 < nend);
    const bool ok1 = (n0 + 1 < nend);
    __syncthreads();
    #pragma unroll
    for (int i = 0; i < 2; ++i) {
      const int u0 = ug * 16 + 8 * i;
      short8 z;
      #pragma unroll
      for (int j = 0; j < 8; ++j) z[j] = 0;
      short8 e0 = z, e1 = z, x0 = z, x1 = z;
      if (ok0) {
        e0 = *(const short8*)(Ebase + (size_t)n0 * KDP + u0);
        x0 = *(const short8*)(Xbase + (size_t)n0 * DP + u0);
      }
      if (ok1) {
        e1 = *(const short8*)(Ebase + (size_t)(n0 + 1) * KDP + u0);
        x1 = *(const short8*)(Xbase + (size_t)(n0 + 1) * DP + u0);
      }
      #pragma unroll
      for (int j = 0; j < 8; ++j) {
        uint32_t ep = (uint32_t)(uint16_t)e0[j] | ((uint32_t)(uint16_t)e1[j] << 16);
        uint32_t xp = (uint32_t)(uint16_t)x0[j] | ((uint32_t)(uint16_t)x1[j] << 16);
        *(uint32_t*)&Es[(u0 + j) * 72 + 2 * np] = ep;
        *(uint32_t*)&Xs[(u0 + j) * 72 + 2 * np] = xp;
      }
    }
    __syncthreads();
    #pragma unroll
    for (int ks = 0; ks < 2; ++ks) {
      const int ko = ks * 32 + q * 8;
      short8 af[4], bfv[4];
      #pragma unroll
      for (int mt = 0; mt < 4; ++mt)
        af[mt] = *(const short8*)&Es[(wm + 16 * mt + l15) * 72 + ko];
      #pragma unroll
      for (int nt = 0; nt < 4; ++nt)
        bfv[nt] = *(const short8*)&Xs[(wn + 16 * nt + l15) * 72 + ko];
      #pragma unroll
      for (int mt = 0; mt < 4; ++mt)
        #pragma unroll
        for (int nt = 0; nt < 4; ++nt)
          acc[mt][nt] = __builtin_amdgcn_mfma_f32_16x16x32_bf16(af[mt], bfv[nt], acc[mt][nt], 0, 0, 0);
    }
  }

  // plain stores to this split's private slab (u>=120 rows are exact zeros
  // since E pad cols are zeroed; fh_red sums them harmlessly)
  float* Fo = Fp + ((size_t)blockIdx.x * BATCH + b) * (KDP * DP);
  #pragma unroll
  for (int nt = 0; nt < 4; ++nt) {
    const int v = wn + 16 * nt + l15;
    #pragma unroll
    for (int mt = 0; mt < 4; ++mt) {
      const int ub = wm + 16 * mt + 4 * q;
      #pragma unroll
      for (int vi = 0; vi < 4; ++vi)
        Fo[(size_t)(ub + vi) * DP + v0 + v] = acc[mt][nt][vi];
    }
  }
}

// ---------------------------------------------------------------------------
// Reduce 16 Fh split-slabs into Fh[f] (float4 per thread)
// ---------------------------------------------------------------------------
__global__ __launch_bounds__(256) void fh_red(const float* __restrict__ Fp, float* __restrict__ Fh) {
  const size_t slab = (size_t)BATCH * KDP * DP;
  size_t idx = ((size_t)blockIdx.x * 256 + threadIdx.x) * 4;
  float4 s = *(const float4*)&Fp[idx];
  #pragma unroll 4
  for (int p = 1; p < FH_S; ++p) {
    float4 v = *(const float4*)&Fp[p * slab + idx];
    s.x += v.x; s.y += v.y; s.z += v.z; s.w += v.w;
  }
  *(float4*)&Fh[idx] = s;
}

// ---------------------------------------------------------------------------
// Gram partials: mat0=FtF, mat1=FtG, mat2=GtG; split-D over GZ chunks of 32,
// plain stores into per-z slabs Gp[z][b*3+mat][120*120] (no global atomics).
// ---------------------------------------------------------------------------
__global__ __launch_bounds__(256) void gram_kern(const float* __restrict__ Fh, float* __restrict__ Gp) {
  __shared__ float As[128 * 33];
  __shared__ float Bs[32 * 132];
  int mat = blockIdx.x, b = blockIdx.y;
  const float* Pa = Fh + (size_t)((mat == 2 ? BATCH : 0) + b) * KDP * DP;
  const float* Pb = Fh + (size_t)((mat == 0 ? 0 : BATCH) + b) * KDP * DP;
  int tid = threadIdx.x;
  int ty = tid >> 4, tx = tid & 15;
  float accv[8][8];
  #pragma unroll
  for (int i = 0; i < 8; ++i)
    #pragma unroll
    for (int j = 0; j < 8; ++j) accv[i][j] = 0.f;
  const int d0 = blockIdx.z * 32;
  #pragma unroll
  for (int j = 0; j < 16; ++j) {
    int e = tid + 256 * j;
    int r = e >> 5, c = e & 31;
    float va = (r < KD) ? Pa[(size_t)r * DP + d0 + c] : 0.f;
    float vb = (r < KD) ? Pb[(size_t)r * DP + d0 + c] : 0.f;
    As[r * 33 + c] = va;
    Bs[c * 132 + r] = vb;
  }
  __syncthreads();
  for (int dd = 0; dd < 32; ++dd) {
    float a[8], bv[8];
    #pragma unroll
    for (int i = 0; i < 8; ++i) a[i] = As[(8 * ty + i) * 33 + dd];
    float4 b0 = *(const float4*)&Bs[dd * 132 + 8 * tx];
    float4 b1 = *(const float4*)&Bs[dd * 132 + 8 * tx + 4];
    bv[0] = b0.x; bv[1] = b0.y; bv[2] = b0.z; bv[3] = b0.w;
    bv[4] = b1.x; bv[5] = b1.y; bv[6] = b1.z; bv[7] = b1.w;
    #pragma unroll
    for (int i = 0; i < 8; ++i)
      #pragma unroll
      for (int j = 0; j < 8; ++j)
        accv[i][j] += a[i] * bv[j];
  }
  float* Go = Gp + ((size_t)blockIdx.z * 24 + (b * 3 + mat)) * (KD * KD);
  #pragma unroll
  for (int i = 0; i < 8; ++i) {
    int k = 8 * ty + i;
    if (k < KD)
      #pragma unroll
      for (int j = 0; j < 8; ++j) {
        int l = 8 * tx + j;
        if (l < KD) Go[k * KD + l] = accv[i][j];
      }
  }
}

// ---------------------------------------------------------------------------
// Reduce GZ gram partial slabs into G (float4 per thread)
// ---------------------------------------------------------------------------
__global__ __launch_bounds__(256) void gram_red(const float* __restrict__ Gp, float* __restrict__ G) {
  const size_t slab = (size_t)24 * KD * KD;
  size_t idx = ((size_t)blockIdx.x * 256 + threadIdx.x) * 4;
  if (idx >= slab) return;
  float4 s = *(const float4*)&Gp[idx];
  #pragma unroll 4
  for (int z = 1; z < GZ; ++z) {
    float4 v = *(const float4*)&Gp[z * slab + idx];
    s.x += v.x; s.y += v.y; s.z += v.z; s.w += v.w;
  }
  *(float4*)&G[idx] = s;
}

// ---------------------------------------------------------------------------
// Fused BLOCKED Cholesky + triangular solves (NB=8 panels, 15 steps each).
// ---------------------------------------------------------------------------
__global__ __launch_bounds__(512) void chol_solve(const float* __restrict__ G, float* __restrict__ out) {
  __shared__ float Ls[KD * 121];
  __shared__ float xs[KD * 128];
  __shared__ float ivs[KD];
  const int sys = blockIdx.x;
  const int b = sys >> 1;
  const int which = sys & 1;
  const int mat = which ? 2 : 0;
  const float* Gm = G + (size_t)(b * 3 + mat) * KD * KD;   // FtF or GtG
  const float* Bm = G + (size_t)(b * 3 + 1) * KD * KD;     // FtG
  const int tid = threadIdx.x;

  for (int e = tid; e < KD * KD; e += 512) {
    int r = e / KD, c = e - r * KD;
    Ls[r * 121 + c] = Gm[e];
  }
  {
    int t = tid & 127, g4 = tid >> 7;
    for (int k = g4; k < KD; k += 4)
      xs[k * 128 + t] = (t < KD) ? (which == 0 ? Bm[k * KD + t] : Bm[t * KD + k]) : 0.f;
  }
  __syncthreads();

  // ---------------- blocked Cholesky ----------------
  for (int kb = 0; kb < NSTEP; ++kb) {
    const int k0 = kb * NB;
    const int m = KD - k0 - NB;   // panel / trailing rows

    float D[NB][NB];
    #pragma unroll
    for (int i = 0; i < NB; ++i)
      #pragma unroll
      for (int j = 0; j <= i; ++j)
        D[i][j] = Ls[(k0 + i) * 121 + k0 + j];
    float di[NB];
    #pragma unroll
    for (int j = 0; j < NB; ++j) {
      float s = sqrtf(D[j][j]);
      float inv = 1.f / s;
      D[j][j] = s; di[j] = inv;
      #pragma unroll
      for (int i = j + 1; i < NB; ++i) D[i][j] *= inv;
      #pragma unroll
      for (int i = j + 1; i < NB; ++i)
        #pragma unroll
        for (int c = j + 1; c <= i; ++c)
          D[i][c] -= D[i][j] * D[c][j];
    }
    if (tid < m) {
      const int i = k0 + NB + tid;
      float a[NB];
      #pragma unroll
      for (int j = 0; j < NB; ++j) a[j] = Ls[i * 121 + k0 + j];
      #pragma unroll
      for (int j = 0; j < NB; ++j) {
        float v = a[j];
        #pragma unroll
        for (int l = 0; l < j; ++l) v -= a[l] * D[j][l];
        a[j] = v * di[j];
      }
      #pragma unroll
      for (int j = 0; j < NB; ++j) Ls[i * 121 + k0 + j] = a[j];
    }
    __syncthreads();

    if (tid == 0) {
      #pragma unroll
      for (int i = 0; i < NB; ++i) {
        #pragma unroll
        for (int j = 0; j <= i; ++j) Ls[(k0 + i) * 121 + k0 + j] = D[i][j];
        ivs[k0 + i] = di[i];
      }
    }
    if (m > 0) {
      const int cq = tid & 31;
      const int g = tid >> 5;
      if (4 * cq < m) {
        const int j0 = k0 + NB + 4 * cq;
        float pc[4][NB];
        #pragma unroll
        for (int qq = 0; qq < 4; ++qq)
          #pragma unroll
          for (int l = 0; l < NB; ++l)
            pc[qq][l] = Ls[(j0 + qq) * 121 + k0 + l];
        for (int i = k0 + NB + g; i < KD; i += 16) {
          float pr[NB];
          #pragma unroll
          for (int l = 0; l < NB; ++l) pr[l] = Ls[i * 121 + k0 + l];
          float* row = &Ls[i * 121 + j0];
          float d0 = row[0], d1 = row[1], d2 = row[2], d3 = row[3];
          #pragma unroll
          for (int l = 0; l < NB; ++l) {
            d0 -= pr[l] * pc[0][l];
            d1 -= pr[l] * pc[1][l];
            d2 -= pr[l] * pc[2][l];
            d3 -= pr[l] * pc[3][l];
          }
          row[0] = d0; row[1] = d1; row[2] = d2; row[3] = d3;
        }
      }
    }
    __syncthreads();
  }

  // ---------------- forward solve: L y = B ----------------
  for (int kb = 0; kb < NSTEP; ++kb) {
    const int k0 = kb * NB;
    if (tid < 128) {
      float Dl[NB][NB];
      #pragma unroll
      for (int i = 1; i < NB; ++i)
        #pragma unroll
        for (int j = 0; j < i; ++j)
          Dl[i][j] = Ls[(k0 + i) * 121 + k0 + j];
      float iv[NB];
      #pragma unroll
      for (int j = 0; j < NB; ++j) iv[j] = ivs[k0 + j];
      float y[NB];
      #pragma unroll
      for (int j = 0; j < NB; ++j) y[j] = xs[(k0 + j) * 128 + tid];
      #pragma unroll
      for (int j = 0; j < NB; ++j) {
        float v = y[j];
        #pragma unroll
        for (int l = 0; l < j; ++l) v -= Dl[j][l] * y[l];
        v *= iv[j];
        y[j] = v;
        xs[(k0 + j) * 128 + tid] = v;
      }
    }
    __syncthreads();
    const int m = KD - k0 - NB;
    if (m > 0) {
      const int cq = tid & 31, g = tid >> 5;
      const int co = 4 * cq;
      float4 v8[NB];
      #pragma unroll
      for (int j = 0; j < NB; ++j) v8[j] = *(const float4*)&xs[(k0 + j) * 128 + co];
      for (int i = k0 + NB + g; i < KD; i += 16) {
        float lp[NB];
        #pragma unroll
        for (int j = 0; j < NB; ++j) lp[j] = Ls[i * 121 + k0 + j];
        float4* dst = (float4*)&xs[i * 128 + co];
        float4 d = *dst;
        #pragma unroll
        for (int j = 0; j < NB; ++j) {
          d.x -= lp[j] * v8[j].x; d.y -= lp[j] * v8[j].y;
          d.z -= lp[j] * v8[j].z; d.w -= lp[j] * v8[j].w;
        }
        *dst = d;
      }
    }
    __syncthreads();
  }

  // ---------------- backward solve: L^T x = y ----------------
  for (int kb = NSTEP - 1; kb >= 0; --kb) {
    const int k0 = kb * NB;
    if (tid < 128) {
      float Dl[NB][NB];
      #pragma unroll
      for (int i = 1; i < NB; ++i)
        #pragma unroll
        for (int j = 0; j < i; ++j)
          Dl[i][j] = Ls[(k0 + i) * 121 + k0 + j];
      float iv[NB];
      #pragma unroll
      for (int j = 0; j < NB; ++j) iv[j] = ivs[k0 + j];
      float y[NB];
      #pragma unroll
      for (int j = 0; j < NB; ++j) y[j] = xs[(k0 + j) * 128 + tid];
      #pragma unroll
      for (int j = NB - 1; j >= 0; --j) {
        float v = y[j];
        #pragma unroll
        for (int l = j + 1; l < NB; ++l) v -= Dl[l][j] * y[l];
        v *= iv[j];
        y[j] = v;
        xs[(k0 + j) * 128 + tid] = v;
      }
    }
    __syncthreads();
    if (k0 > 0) {
      const int cq = tid & 31, g = tid >> 5;
      const int co = 4 * cq;
      float4 v8[NB];
      #pragma unroll
      for (int j = 0; j < NB; ++j) v8[j] = *(const float4*)&xs[(k0 + j) * 128 + co];
      for (int i = g; i < k0; i += 16) {
        float lp[NB];
        #pragma unroll
        for (int j = 0; j < NB; ++j) lp[j] = Ls[(k0 + j) * 121 + i];
        float4* dst = (float4*)&xs[i * 128 + co];
        float4 d = *dst;
        #pragma unroll
        for (int j = 0; j < NB; ++j) {
          d.x -= lp[j] * v8[j].x; d.y -= lp[j] * v8[j].y;
          d.z -= lp[j] * v8[j].z; d.w -= lp[j] * v8[j].w;
        }
        *dst = d;
      }
    }
    __syncthreads();
  }

  // output: Co[t][k] = xs[k][t]  (x fully scaled)
  float* Co = out + (size_t)which * BATCH * KD * KD + (size_t)b * KD * KD;
  {
    int t = tid & 127, gg = tid >> 7;
    if (t < KD)
      for (int k = gg; k < KD; k += 4)
        Co[(size_t)t * KD + k] = xs[k * 128 + t];
  }
}

// ---------------------------------------------------------------------------
extern "C" void kernel_launch(void* const* d_in, const int* in_sizes, int n_in,
                              void* d_out, int out_size, void* d_ws, size_t ws_size,
                              hipStream_t stream) {
  (void)in_sizes; (void)n_in; (void)out_size; (void)ws_size;
  const float* feat_x = (const float*)d_in[0];
  const float* feat_y = (const float*)d_in[1];
  const float* evecs_x = (const float*)d_in[2];
  const float* evecs_y = (const float*)d_in[3];
  const float* W1 = (const float*)d_in[4];
  const float* b1 = (const float*)d_in[5];
  const float* W2 = (const float*)d_in[6];
  const float* b2 = (const float*)d_in[7];
  const float* gamma = (const float*)d_in[8];
  const float* beta = (const float*)d_in[9];
  float* out = (float*)d_out;

  char* p = (char*)d_ws;
  auto carve = [&](size_t bytes) { char* r = p; p += (bytes + 255) & ~(size_t)255; return r; };
  short* W1t = (short*)carve(7ull * DP * DP * 2);
  short* W2t = (short*)carve(7ull * DP * DP * 2);
  short* X  = (short*)carve((size_t)RROWS * DP * 2);
  short* T1 = (short*)carve((size_t)RROWS * DP * 2);
  short* T2 = (short*)carve((size_t)RROWS * DP * 2);
  short* Eb = (short*)carve((size_t)BATCH * NVERT * KDP * 2);
  float* stats = (float*)carve(4ull * DP * 4);
  float* Fh = (float*)carve(2ull * BATCH * KDP * DP * 4);
  float* Fp = (float*)carve((size_t)FH_S * BATCH * KDP * DP * 4);   // 25.2 MB, reused per f
  float* gram = (float*)carve((size_t)BATCH * 3 * KD * KD * 4);
  float* Gp = (float*)carve((size_t)GZ * 24 * KD * KD * 4);          // 16.6 MB
  float* statsA = stats;
  float* statsB = stats + 2 * DP;

  prep_w<<<dim3((7 * DP * DP) / 256, 2), 256, 0, stream>>>(W1, W2, W1t, W2t);

  const int MT = (RROWS + 127) / 128;  // 431
  const int ET = (NVERT * 16 + 255) / 256;  // 431
  const int FRED = (BATCH * KDP * DP / 4) / 256;  // 384
  for (int f = 0; f < 2; ++f) {
    const float* feat = f ? feat_y : feat_x;
    const float* ev = f ? evecs_y : evecs_x;
    float* fxo = out + 2 * BATCH * KD * KD + (size_t)f * RROWS * DIN;
    cast_in<<<MT, 192, 0, stream>>>(feat, X, statsA);
    cast_e<<<dim3(ET, BATCH), 256, 0, stream>>>(ev, Eb);
    for (int blk = 0; blk < NBLK; ++blk) {
      // gemm1: plain A=X, accumulate statsA; zero statsB (idle this kernel)
      gemm_bn<<<GEMM_WG, 256, 0, stream>>>(X, W1t + (size_t)blk * DP * DP, T1, b1 + blk * DIN,
                                           statsA, statsB);
      // gemm2: fused elt_bn (affine+relu from statsA) on A=T1, accumulate statsB
      gemm_bn_f<<<GEMM_WG, 256, 0, stream>>>(T1, W2t + (size_t)blk * DP * DP, T2, b2 + blk * DIN,
                                             statsB, statsA, gamma + blk * DIN, beta + blk * DIN);
      // residual: X = relu(bn(T2) + X); zero statsA for next block's gemm1
      elt_res<<<MT, 192, 0, stream>>>(T2, X, statsB, gamma + blk * DIN, beta + blk * DIN, statsA,
                                      (blk == NBLK - 1) ? fxo : (float*)nullptr);
    }
    fh_mfma<<<dim3(FH_S, 3, BATCH), 256, 0, stream>>>(Eb, X, Fp);
    fh_red<<<FRED, 256, 0, stream>>>(Fp, Fh + (size_t)f * BATCH * KDP * DP);
  }
  gram_kern<<<dim3(3, BATCH, GZ), 256, 0, stream>>>(Fh, Gp);
  gram_red<<<(24 * KD * KD / 4 + 255) / 256, 256, 0, stream>>>(Gp, gram);
  chol_solve<<<16, 512, 0, stream>>>(gram, out);
}